// Round 14
// baseline (460.378 us; speedup 1.0000x reference)
//
#include <hip/hip_runtime.h>
#include <cstdint>
#include <cstddef>

#define D 64
#define SMAX 24
#define PCHUNK 8192
#define BCAP 12288

typedef __attribute__((ext_vector_type(8))) short short8;
typedef __attribute__((ext_vector_type(4))) float floatx4;
typedef __attribute__((ext_vector_type(2))) float floatx2;
typedef __attribute__((ext_vector_type(8))) _Float16 half8v;

__device__ inline unsigned short f2bf(float f) {   // RNE fp32 -> bf16
    unsigned u = __float_as_uint(f);
    unsigned r = 0x7FFFu + ((u >> 16) & 1u);
    return (unsigned short)((u + r) >> 16);
}
__device__ inline float bf2f(unsigned short h) {
    return __uint_as_float(((unsigned)h) << 16);
}
__device__ inline unsigned char f2fp8(float f) {   // fp32 -> fp8 e4m3 (OCP on gfx950)
    int pk = __builtin_amdgcn_cvt_pk_fp8_f32(f, f, 0, false);
    return (unsigned char)(pk & 0xFF);
}

// ---------------- bucket-partition CSR build ----------------

__global__ void k_hist(const int* __restrict__ col, int* __restrict__ ghist,
                       int E, int NBK) {
    extern __shared__ int lh[];
    int t = threadIdx.x;
    for (int i = t; i < NBK; i += 256) lh[i] = 0;
    __syncthreads();
    int base = blockIdx.x * 8192;
    int end = base + 8192; if (end > E) end = E;
    for (int e = base + t; e < end; e += 256) atomicAdd(&lh[col[e] >> 8], 1);
    __syncthreads();
    for (int i = t; i < NBK; i += 256) if (lh[i]) atomicAdd(&ghist[i], lh[i]);
}

__global__ void k_bscan(const int* __restrict__ ghist, int* __restrict__ bstart,
                        int* __restrict__ gcur, int* __restrict__ offs,
                        int NBK, int N, int E) {
    __shared__ int s[512];
    int t = threadIdx.x;
    int v = (t < NBK) ? ghist[t] : 0;
    s[t] = v; __syncthreads();
    for (int off = 1; off < 512; off <<= 1) {
        int x = (t >= off) ? s[t - off] : 0;
        __syncthreads();
        s[t] += x;
        __syncthreads();
    }
    int excl = s[t] - v;
    if (t < NBK) { bstart[t] = excl; gcur[t] = excl; }
    if (t == 0) { bstart[NBK] = E; offs[N] = E; }
}

// Block-level counting sort: each 8192-edge chunk is sorted by bucket (col>>8)
// in LDS, then written out coalesced. Record packed to 4B: (row<<8)|(col&255).
__global__ __launch_bounds__(512) void k_part(const int* __restrict__ row,
                                              const int* __restrict__ col,
                                              int* __restrict__ gcur,
                                              unsigned* __restrict__ part,
                                              int E, int NBK) {
    extern __shared__ int sm[];
    int* cnt    = sm;                  // NBK: per-bucket count
    int* cursor = sm + NBK;            // NBK: scatter cursor (starts at lstart)
    int* delta  = sm + 2 * NBK;        // NBK: gbase - lstart
    int* s      = sm + 3 * NBK;        // 512: scan buffer
    unsigned* sbuf = (unsigned*)(sm + 3 * NBK + 512);       // PCHUNK sorted records
    unsigned short* bkt = (unsigned short*)(sbuf + PCHUNK); // PCHUNK bucket ids

    int t = threadIdx.x;
    int base = blockIdx.x * PCHUNK;
    int end = base + PCHUNK; if (end > E) end = E;
    int nloc = end - base;

    for (int i = t; i < NBK; i += 512) cnt[i] = 0;
    __syncthreads();

    // pass 1: read col (once), histogram, keep col in registers
    int carr[16];
#pragma unroll
    for (int i = 0; i < 16; ++i) {
        int e = base + t + i * 512;
        int c = -1;
        if (e < end) {
            c = col[e];
            atomicAdd(&cnt[c >> 8], 1);
        }
        carr[i] = c;
    }
    __syncthreads();

    // exclusive scan over NBK buckets (512-wide Hillis-Steele, 1 elem/thread)
    int v0 = (t < NBK) ? cnt[t] : 0;
    s[t] = v0;
    __syncthreads();
    for (int off = 1; off < 512; off <<= 1) {
        int x = (t >= off) ? s[t - off] : 0;
        __syncthreads();
        s[t] += x;
        __syncthreads();
    }
    // s[i] inclusive; lstart = s[i] - cnt[i]. Reserve global ranges.
    for (int i = t; i < NBK; i += 512) {
        int c = cnt[i];
        int lst = s[i] - c;
        cursor[i] = lst;
        int gb = c ? atomicAdd(&gcur[i], c) : 0;
        delta[i] = gb - lst;
    }
    __syncthreads();

    // pass 2: read row (once), scatter packed record into LDS sorted order
#pragma unroll
    for (int i = 0; i < 16; ++i) {
        int c = carr[i];
        if (c >= 0) {
            int e = base + t + i * 512;
            int b = c >> 8;
            int p = atomicAdd(&cursor[b], 1);
            sbuf[p] = ((unsigned)row[e] << 8) | (unsigned)(c & 255);
            bkt[p] = (unsigned short)b;
        }
    }
    __syncthreads();

    // writeout: consecutive lanes -> consecutive global addresses per run
    for (int p = t; p < nloc; p += 512) {
        int b = bkt[p];
        part[p + delta[b]] = sbuf[p];
    }
}

// Per-bucket CSR finalize. csrc stores BYTE offsets into the fp8 xw table (row<<6).
__global__ __launch_bounds__(256) void k_bucket(const unsigned* __restrict__ part,
                                                const int* __restrict__ bstart,
                                                int* __restrict__ offs,
                                                float* __restrict__ dis,
                                                int* __restrict__ csrc, int N) {
    __shared__ int ncnt[256];
    __shared__ int s[256];
    __shared__ int lcur[256];
    __shared__ unsigned sb[BCAP];
    int b = blockIdx.x;
    int t = threadIdx.x;
    int n0 = b << 8;
    int e0 = bstart[b], e1 = bstart[b + 1];
    int nloc = e1 - e0;
    bool fits = nloc <= BCAP;
    ncnt[t] = 0;
    __syncthreads();
    if (fits) {
        for (int e = t; e < nloc; e += 256) {
            unsigned pr = part[e0 + e];
            sb[e] = pr;
            atomicAdd(&ncnt[pr & 255u], 1);
        }
    } else {
        for (int e = e0 + t; e < e1; e += 256) {
            unsigned pr = part[e];
            atomicAdd(&ncnt[pr & 255u], 1);
        }
    }
    __syncthreads();
    int v = ncnt[t];
    s[t] = v; __syncthreads();
    for (int off = 1; off < 256; off <<= 1) {
        int x = (t >= off) ? s[t - off] : 0;
        __syncthreads();
        s[t] += x;
        __syncthreads();
    }
    int excl = s[t] - v;
    int node = n0 + t;
    if (node < N) {
        offs[node] = e0 + excl;
        dis[node] = rsqrtf((float)(v + 1));
    }
    lcur[t] = excl;
    __syncthreads();
    if (fits) {
        for (int e = t; e < nloc; e += 256) {
            unsigned pr = sb[e];
            int p = atomicAdd(&lcur[pr & 255u], 1);
            csrc[e0 + p] = (int)(pr >> 8) << 6;
        }
    } else {
        for (int e = e0 + t; e < e1; e += 256) {
            unsigned pr = part[e];
            int p = atomicAdd(&lcur[pr & 255u], 1);
            csrc[e0 + p] = (int)(pr >> 8) << 6;
        }
    }
}

// graph boundaries
__global__ void k_gb(const int* __restrict__ batch, int* __restrict__ gstart,
                     int N, int G) {
    int g = threadIdx.x;
    if (g > G) return;
    int lo = 0, hi = N;
    while (lo < hi) {
        int mid = (lo + hi) >> 1;
        if (batch[mid] < g) lo = mid + 1; else hi = mid;
    }
    gstart[g] = lo;
}

// fold BN (eval) + conv bias into per-channel scale/shift
__global__ void k_bnprep(const float* __restrict__ cb, const float* __restrict__ g,
                         const float* __restrict__ be, const float* __restrict__ mu,
                         const float* __restrict__ var, float* __restrict__ sc,
                         float* __restrict__ sh, int LD) {
    int i = blockIdx.x * 256 + threadIdx.x;
    if (i < LD) {
        float s = g[i] * rsqrtf(var[i] + 1e-5f);
        sc[i] = s;
        sh[i] = (cb[i] - mu[i]) * s + be[i];
    }
}

// split fp32 weights into bf16 hi/lo, packed in MFMA fragment order:
// (k,n) -> chunk c=k/32, ntile=n/64, j=(n&63)>>4, lane=((k&31)>>3)*16+(n&15), kidx=k&7
__global__ void k_wpack(const float* __restrict__ B, unsigned short* __restrict__ hiP,
                        unsigned short* __restrict__ loP, int K, int Nc, int nshift) {
    int idx = blockIdx.x * 256 + threadIdx.x;
    if (idx >= K * Nc) return;
    int k = idx >> nshift;
    int n = idx & (Nc - 1);
    float a = B[idx];
    unsigned b = __float_as_uint(a);
    unsigned hb = b & 0xFFFF0000u;
    float ah = __uint_as_float(hb);
    float al = a - ah;
    int c = k >> 5;
    int ntile = n >> 6;
    int j = (n & 63) >> 4;
    int lane = ((k & 31) >> 3) * 16 + (n & 15);
    int kidx = k & 7;
    size_t o = ((((size_t)c * (Nc >> 6) + ntile) * 4 + j) * 64 + lane) * 8 + kidx;
    hiP[o] = (unsigned short)(hb >> 16);
    loP[o] = (unsigned short)(__float_as_uint(al) >> 16);
}

// bf16-only (RNE) fragment-packed weights (encoder)
__global__ void k_wpackb(const float* __restrict__ B, unsigned short* __restrict__ P,
                         int K, int Nc, int nshift) {
    int idx = blockIdx.x * 256 + threadIdx.x;
    if (idx >= K * Nc) return;
    int k = idx >> nshift;
    int n = idx & (Nc - 1);
    int c = k >> 5;
    int ntile = n >> 6;
    int j = (n & 63) >> 4;
    int lane = ((k & 31) >> 3) * 16 + (n & 15);
    int kidx = k & 7;
    size_t o = ((((size_t)c * (Nc >> 6) + ntile) * 4 + j) * 64 + lane) * 8 + kidx;
    P[o] = f2bf(B[idx]);
}

// cast fp32 -> bf16 (RNE), 8 elems/thread
__global__ void k_cast(const float* __restrict__ x, unsigned short* __restrict__ xb,
                       int n8) {
    int i = blockIdx.x * 256 + threadIdx.x;
    if (i >= n8) return;
    const float4* p = (const float4*)(x + (size_t)i * 8);
    float4 v0 = p[0], v1 = p[1];
    short8 o;
    o[0] = (short)f2bf(v0.x); o[1] = (short)f2bf(v0.y);
    o[2] = (short)f2bf(v0.z); o[3] = (short)f2bf(v0.w);
    o[4] = (short)f2bf(v1.x); o[5] = (short)f2bf(v1.y);
    o[6] = (short)f2bf(v1.z); o[7] = (short)f2bf(v1.w);
    *(short8*)(xb + (size_t)i * 8) = o;
}

// ---------------- conv GEMM via MFMA: xw' = fp8((A_bf16 @ (Whi+Wlo)) * dis[row]) ----------------
// K=64 (2 chunks, fully unrolled). Wave tile m=32 x n=64. Block = 4 waves -> BM=128.

__global__ __launch_bounds__(256) void k_convm(const unsigned short* __restrict__ A,
                                               const unsigned short* __restrict__ Whi,
                                               const unsigned short* __restrict__ Wlo,
                                               const float* __restrict__ dis,
                                               unsigned char* __restrict__ out, int N) {
    int t = threadIdx.x;
    int lane = t & 63;
    int l16 = lane & 15;
    int quad = lane >> 4;
    int w = t >> 6;
    int bm = blockIdx.x * 128 + w * 32;

    floatx4 acc[2][4];
#pragma unroll
    for (int i = 0; i < 2; ++i)
#pragma unroll
        for (int j = 0; j < 4; ++j) acc[i][j] = (floatx4)0.f;

    int r0 = bm + l16; if (r0 > N - 1) r0 = N - 1;
    int r1 = bm + 16 + l16; if (r1 > N - 1) r1 = N - 1;
    const unsigned short* a0 = A + (size_t)r0 * 64 + quad * 8;
    const unsigned short* a1 = A + (size_t)r1 * 64 + quad * 8;
    const unsigned short* bp = Whi + lane * 8;
    size_t loOff = (size_t)(Wlo - Whi);

    short8 a0c[2], a1c[2], bh[2][4], bl[2][4];
#pragma unroll
    for (int c = 0; c < 2; ++c) {
        a0c[c] = *(const short8*)(a0 + c * 32);
        a1c[c] = *(const short8*)(a1 + c * 32);
#pragma unroll
        for (int j = 0; j < 4; ++j) {
            bh[c][j] = *(const short8*)(bp + c * 2048 + j * 512);
            bl[c][j] = *(const short8*)(bp + loOff + c * 2048 + j * 512);
        }
    }
#pragma unroll
    for (int c = 0; c < 2; ++c) {
#pragma unroll
        for (int j = 0; j < 4; ++j) {
            acc[0][j] = __builtin_amdgcn_mfma_f32_16x16x32_bf16(a0c[c], bl[c][j], acc[0][j], 0, 0, 0);
            acc[0][j] = __builtin_amdgcn_mfma_f32_16x16x32_bf16(a0c[c], bh[c][j], acc[0][j], 0, 0, 0);
            acc[1][j] = __builtin_amdgcn_mfma_f32_16x16x32_bf16(a1c[c], bl[c][j], acc[1][j], 0, 0, 0);
            acc[1][j] = __builtin_amdgcn_mfma_f32_16x16x32_bf16(a1c[c], bh[c][j], acc[1][j], 0, 0, 0);
        }
    }
#pragma unroll
    for (int i = 0; i < 2; ++i) {
#pragma unroll
        for (int r = 0; r < 4; ++r) {
            int m = bm + i * 16 + quad * 4 + r;
            if (m < N) {
                float dv = dis[m];
                unsigned char* op = out + (size_t)m * 64 + l16;
#pragma unroll
                for (int j = 0; j < 4; ++j)
                    op[j * 16] = f2fp8(acc[i][j][r] * dv);
            }
        }
    }
}

// ---------------- aggregation: 8 nodes/wave, 8 chan-lanes per node, fp8 table ----------------

__global__ __launch_bounds__(256) void k_agg(const unsigned char* __restrict__ xw,
                                             const int* __restrict__ offs,
                                             const int* __restrict__ src,
                                             const float* __restrict__ dis,
                                             const float* __restrict__ sc,
                                             const float* __restrict__ sh,
                                             const float* __restrict__ skip,
                                             float* __restrict__ out,
                                             unsigned short* __restrict__ outb,
                                             int N) {
    int t = threadIdx.x;
    int lane = t & 63;
    int w = t >> 6;
    int g = lane >> 3;          // node slot 0..7 within wave
    int cg = lane & 7;          // channel group: 8 fp8 channels (8 B)
    int c0 = cg * 8;
    int v = blockIdx.x * 32 + w * 8 + g;
    int vc = (v < N) ? v : N - 1;
    int e0 = offs[vc], e1 = offs[vc + 1];
    int deg = (v < N) ? (e1 - e0) : 0;
    const int* sp = src + e0;
    const unsigned char* xb = xw + (cg << 3);
    int zoff = N << 6;          // zero row (row N of xw is zeroed)

    // wave-max degree across the 8 node groups
    int dm = deg;
    dm = max(dm, __shfl_xor(dm, 8));
    dm = max(dm, __shfl_xor(dm, 16));
    dm = max(dm, __shfl_xor(dm, 32));

    floatx2 a01 = (floatx2)0.f, a23 = (floatx2)0.f;
    floatx2 a45 = (floatx2)0.f, a67 = (floatx2)0.f;

    int gbase = g << 3;
    for (int k = 0; k < dm; k += 8) {
        int idx = k + cg;
        int sv = sp[(idx < deg) ? idx : 0];     // coalesced: 8 consecutive srcs/group
        uint2 m[8];
#pragma unroll
        for (int j = 0; j < 8; ++j) {
            int o = __shfl(sv, gbase + j);
            o = (k + j < deg) ? o : zoff;
            m[j] = *(const uint2*)(xb + o);
        }
#pragma unroll
        for (int j = 0; j < 8; ++j) {
            a01 += __builtin_amdgcn_cvt_pk_f32_fp8(m[j].x, false);
            a23 += __builtin_amdgcn_cvt_pk_f32_fp8(m[j].x, true);
            a45 += __builtin_amdgcn_cvt_pk_f32_fp8(m[j].y, false);
            a67 += __builtin_amdgcn_cvt_pk_f32_fp8(m[j].y, true);
        }
    }

    if (v < N) {
        uint2 ar = *(const uint2*)(xb + ((size_t)vc << 6));   // self loop
        a01 += __builtin_amdgcn_cvt_pk_f32_fp8(ar.x, false);
        a23 += __builtin_amdgcn_cvt_pk_f32_fp8(ar.x, true);
        a45 += __builtin_amdgcn_cvt_pk_f32_fp8(ar.y, false);
        a67 += __builtin_amdgcn_cvt_pk_f32_fp8(ar.y, true);
        float u[8];
        u[0] = a01[0]; u[1] = a01[1]; u[2] = a23[0]; u[3] = a23[1];
        u[4] = a45[0]; u[5] = a45[1]; u[6] = a67[0]; u[7] = a67[1];
        float dv = dis[vc];
        float4 S0 = *(const float4*)&sc[c0];
        float4 S1 = *(const float4*)&sc[c0 + 4];
        float4 H0 = *(const float4*)&sh[c0];
        float4 H1 = *(const float4*)&sh[c0 + 4];
        float sv[8], hv[8];
        sv[0] = S0.x; sv[1] = S0.y; sv[2] = S0.z; sv[3] = S0.w;
        sv[4] = S1.x; sv[5] = S1.y; sv[6] = S1.z; sv[7] = S1.w;
        hv[0] = H0.x; hv[1] = H0.y; hv[2] = H0.z; hv[3] = H0.w;
        hv[4] = H1.x; hv[5] = H1.y; hv[6] = H1.z; hv[7] = H1.w;
        float y[8];
#pragma unroll
        for (int q = 0; q < 8; ++q)
            y[q] = fmaxf(fmaf(u[q] * dv, sv[q], hv[q]), 0.f);
        size_t ob = (size_t)v * 64 + c0;
        if (skip) {
            float4 k0v = *(const float4*)(skip + ob);
            float4 k1v = *(const float4*)(skip + ob + 4);
            y[0] += k0v.x; y[1] += k0v.y; y[2] += k0v.z; y[3] += k0v.w;
            y[4] += k1v.x; y[5] += k1v.y; y[6] += k1v.z; y[7] += k1v.w;
        }
        if (out) {
            float4 o0, o1;
            o0.x = y[0]; o0.y = y[1]; o0.z = y[2]; o0.w = y[3];
            o1.x = y[4]; o1.y = y[5]; o1.z = y[6]; o1.w = y[7];
            *(float4*)(out + ob) = o0;
            *(float4*)(out + ob + 4) = o1;
        }
        short8 b8;
#pragma unroll
        for (int q = 0; q < 8; ++q) b8[q] = (short)f2bf(y[q]);
        *(short8*)(outb + ob) = b8;
    }
}

// ---------------- fused encoder + pool: h2 = relu(relu(A@W1+b1)@W2+b2), pooled into gsum ----
// BM=64 rows/block, 512 threads (8 waves = 2 row-groups x 4 col-waves) to halve the
// per-row W1/W2 L2 line traffic (k_enc was weight-refetch bound at BM=32).
// enc1: wave (mg,nw) computes h1[32mg:32mg+32)[64nw:64nw+64); h1 -> LDS (A buffer reused).
// enc2: wave (mg,nw) computes h2[32mg:32mg+32)[32nw:32nw+32). Rows segment-reduced by
// graph (batch sorted; <=2 segments per 64-row block expected, atomic fallback otherwise)
// and added into gsum[G][128].

__global__ __launch_bounds__(512) void k_enc(const unsigned short* __restrict__ A,
                                             size_t pplane, int M,
                                             const unsigned short* __restrict__ BP1,
                                             const float* __restrict__ bias1,
                                             const unsigned short* __restrict__ BP2,
                                             const float* __restrict__ bias2,
                                             const int* __restrict__ batch,
                                             float* __restrict__ gsum) {
    __shared__ unsigned short As[64 * 264];   // A tile [64][256+8]; later h1 tile
    __shared__ int bt[64];
    __shared__ int badf;
    const int KP = 264;
    int t = threadIdx.x;
    int lane = t & 63;
    int l16 = lane & 15;
    int quad = lane >> 4;
    int w = t >> 6;          // 0..7
    int nw = w & 3;          // col-wave
    int mg = w >> 2;         // row-group
    int bm = blockIdx.x * 64;

    if (t == 0) badf = 0;
    if (t < 64) bt[t] = batch[min(bm + t, M - 1)];

    // stage A tile: 64 rows x 256 cols from 4 planes (coalesced 16B segments)
    for (int q = t; q < 2048; q += 512) {
        int r = q >> 5;
        int s = q & 31;
        int gr = bm + r; if (gr > M - 1) gr = M - 1;
        int p = s >> 3;
        int i = s & 7;
        *(short8*)(As + r * KP + s * 8) =
            *(const short8*)(A + (size_t)p * pplane + (size_t)gr * 64 + i * 8);
    }
    __syncthreads();

    if (t < 64) {
        int b = bt[t];
        if (b != bt[0] && b != bt[63]) badf = 1;   // >2 segments: pathological
    }

    // ---- enc1: wave (mg,nw) computes h1[32mg..][64nw..64nw+64), K=256 (NC=8) ----
    int n0 = nw * 64;
    floatx4 acc[2][4];
#pragma unroll
    for (int i = 0; i < 2; ++i)
#pragma unroll
        for (int j = 0; j < 4; ++j) acc[i][j] = (floatx4)0.f;

    const unsigned short* a0 = As + (mg * 32 + l16) * KP + quad * 8;
    const unsigned short* a1 = a0 + 16 * KP;
    const unsigned short* bp1 = BP1 + ((size_t)(n0 >> 6) * 4) * 512 + lane * 8;

    short8 B[2][4];
#pragma unroll
    for (int s = 0; s < 2; ++s)
#pragma unroll
        for (int j = 0; j < 4; ++j)
            B[s][j] = *(const short8*)(bp1 + (size_t)s * 8192 + j * 512);

    for (int c = 0; c < 8; ++c) {
        int nc = (c + 2 < 8) ? c + 2 : 7;
        short8 tB[4];
#pragma unroll
        for (int j = 0; j < 4; ++j)
            tB[j] = *(const short8*)(bp1 + (size_t)nc * 8192 + j * 512);
        short8 A0 = *(const short8*)(a0 + c * 32);
        short8 A1 = *(const short8*)(a1 + c * 32);
#pragma unroll
        for (int j = 0; j < 4; ++j) {
            acc[0][j] = __builtin_amdgcn_mfma_f32_16x16x32_bf16(A0, B[0][j], acc[0][j], 0, 0, 0);
            acc[1][j] = __builtin_amdgcn_mfma_f32_16x16x32_bf16(A1, B[0][j], acc[1][j], 0, 0, 0);
        }
#pragma unroll
        for (int j = 0; j < 4; ++j) B[0][j] = B[1][j];
#pragma unroll
        for (int j = 0; j < 4; ++j) B[1][j] = tB[j];
    }

    __syncthreads();   // all waves done reading the A tile

    // write h1 = relu(acc + b1) as bf16 into As (row-major [64][256], KP pad kept)
#pragma unroll
    for (int i = 0; i < 2; ++i)
#pragma unroll
        for (int r = 0; r < 4; ++r) {
            int ml = mg * 32 + i * 16 + quad * 4 + r;
#pragma unroll
            for (int j = 0; j < 4; ++j) {
                float y = fmaxf(acc[i][j][r] + bias1[n0 + j * 16 + l16], 0.f);
                As[ml * KP + n0 + j * 16 + l16] = f2bf(y);
            }
        }
    __syncthreads();

    // ---- enc2: wave (mg,nw) computes h2[32mg..][32nw..32nw+32), K=256 (NC=8) ----
    int n0b = nw * 32;
    floatx4 acc2[2][2];
#pragma unroll
    for (int i = 0; i < 2; ++i)
#pragma unroll
        for (int j = 0; j < 2; ++j) acc2[i][j] = (floatx4)0.f;

    const unsigned short* bp2 = BP2 +
        ((size_t)((n0b >> 6) * 4 + ((n0b & 63) >> 4))) * 512 + lane * 8;

    for (int c = 0; c < 8; ++c) {
        short8 A0 = *(const short8*)(a0 + c * 32);
        short8 A1 = *(const short8*)(a1 + c * 32);
        short8 B0 = *(const short8*)(bp2 + (size_t)c * 4096);
        short8 B1 = *(const short8*)(bp2 + (size_t)c * 4096 + 512);
        acc2[0][0] = __builtin_amdgcn_mfma_f32_16x16x32_bf16(A0, B0, acc2[0][0], 0, 0, 0);
        acc2[0][1] = __builtin_amdgcn_mfma_f32_16x16x32_bf16(A0, B1, acc2[0][1], 0, 0, 0);
        acc2[1][0] = __builtin_amdgcn_mfma_f32_16x16x32_bf16(A1, B0, acc2[1][0], 0, 0, 0);
        acc2[1][1] = __builtin_amdgcn_mfma_f32_16x16x32_bf16(A1, B1, acc2[1][1], 0, 0, 0);
    }

    // ---- pooled epilogue: segment-reduce rows by graph, atomicAdd into gsum ----
    int g0 = bt[0], g1 = bt[63];
    if (!badf) {
#pragma unroll
        for (int j = 0; j < 2; ++j) {
            float s0 = 0.f, s1 = 0.f;
#pragma unroll
            for (int i = 0; i < 2; ++i)
#pragma unroll
                for (int r = 0; r < 4; ++r) {
                    int ml = mg * 32 + i * 16 + quad * 4 + r;
                    if (bm + ml < M) {
                        float y = fmaxf(acc2[i][j][r] + bias2[n0b + j * 16 + l16], 0.f);
                        bool f = (bt[ml] != g0);
                        s0 += f ? 0.f : y;
                        s1 += f ? y : 0.f;
                    }
                }
            s0 += __shfl_xor(s0, 16); s0 += __shfl_xor(s0, 32);
            s1 += __shfl_xor(s1, 16); s1 += __shfl_xor(s1, 32);
            if (quad == 0) {
                int cb = n0b + j * 16 + l16;
                atomicAdd(&gsum[(size_t)g0 * 128 + cb], s0);
                if (g1 != g0) atomicAdd(&gsum[(size_t)g1 * 128 + cb], s1);
            }
        }
    } else {
#pragma unroll
        for (int j = 0; j < 2; ++j)
#pragma unroll
            for (int i = 0; i < 2; ++i)
#pragma unroll
                for (int r = 0; r < 4; ++r) {
                    int ml = mg * 32 + i * 16 + quad * 4 + r;
                    if (bm + ml < M) {
                        float y = fmaxf(acc2[i][j][r] + bias2[n0b + j * 16 + l16], 0.f);
                        atomicAdd(&gsum[(size_t)bt[ml] * 128 + n0b + j * 16 + l16], y);
                    }
                }
    }
}

// ---------------- decoder: 4 waves x 32-k-chunk, fully unrolled (H=128, HD=64) ----------------

__global__ __launch_bounds__(256) void k_dec(const float* __restrict__ gsum, const int* __restrict__ gstart,
                      const float* __restrict__ W1, const float* __restrict__ b1,
                      const float* __restrict__ W2, const float* __restrict__ b2,
                      float* __restrict__ out, int H, int HD) {
    __shared__ float red[4][64];
    int g = blockIdx.x;
    int t = threadIdx.x;
    int c = t & 63;
    int kk = t >> 6;
    float cnt = (float)(gstart[g + 1] - gstart[g]);
    float inv = 1.0f / fmaxf(cnt, 1.0f);
    const float* gp = gsum + (size_t)g * 128 + kk * 32;
    const float* wp = W1 + (size_t)(kk * 32) * 64 + c;
    float a0 = 0.f, a1 = 0.f, a2 = 0.f, a3 = 0.f;
#pragma unroll
    for (int j = 0; j < 32; j += 4) {
        float g0 = gp[j + 0], g1 = gp[j + 1], g2 = gp[j + 2], g3 = gp[j + 3];
        float w0 = wp[(j + 0) * 64], w1 = wp[(j + 1) * 64];
        float w2 = wp[(j + 2) * 64], w3 = wp[(j + 3) * 64];
        a0 = fmaf(g0, w0, a0);
        a1 = fmaf(g1, w1, a1);
        a2 = fmaf(g2, w2, a2);
        a3 = fmaf(g3, w3, a3);
    }
    red[kk][c] = (a0 + a1) + (a2 + a3);
    __syncthreads();
    if (kk == 0) {
        float hid = ((red[0][c] + red[1][c]) + (red[2][c] + red[3][c])) * inv + b1[c];
        hid = fmaxf(hid, 0.f);
        float p = hid * W2[c];
        for (int off = 32; off > 0; off >>= 1) p += __shfl_down(p, off);
        if (c == 0) out[g] = p + b2[0];
    }
}

// ---------------- host ----------------

extern "C" void kernel_launch(void* const* d_in, const int* in_sizes, int n_in,
                              void* d_out, int out_size, void* d_ws, size_t ws_size,
                              hipStream_t stream) {
    const float* x     = (const float*)d_in[0];
    const int*   ei    = (const int*)d_in[1];
    const int*   batch = (const int*)d_in[2];
    const float* convW = (const float*)d_in[3];
    const float* convb = (const float*)d_in[4];
    const float* gamma = (const float*)d_in[5];
    const float* beta  = (const float*)d_in[6];
    const float* mean  = (const float*)d_in[7];
    const float* var   = (const float*)d_in[8];
    const float* eW1   = (const float*)d_in[9];
    const float* eb1   = (const float*)d_in[10];
    const float* eW2   = (const float*)d_in[11];
    const float* eb2   = (const float*)d_in[12];
    const float* dW1   = (const float*)d_in[13];
    const float* db1   = (const float*)d_in[14];
    const float* dW2   = (const float*)d_in[15];
    const float* db2   = (const float*)d_in[16];

    int N  = in_sizes[0] / D;
    int E  = in_sizes[1] / 2;
    int L  = in_sizes[3] / (D * D);
    int G  = out_size;
    int LD = L * D;                 // 256
    int H1 = in_sizes[10];          // 256
    int H2 = in_sizes[12];          // 128
    int HD = in_sizes[14];          // 64
    int NBK = (N + 255) >> 8;       // 391

    char* ws = (char*)d_ws;
    size_t off = 0;
    auto alloc = [&](size_t b) -> void* {
        void* p = ws + off;
        off += (b + 255) & ~(size_t)255;
        return p;
    };
    float* local  = (float*)alloc((size_t)N * D * 4);         // fp32 layer0 plane (skip source)
    unsigned short* localb = (unsigned short*)alloc((size_t)N * LD * 2);  // bf16 planes [L][N][64]
    char*  bufB   = (char*)alloc((size_t)(N + 1) * LD * 2);   // part / xw fp8 (+zero row)
    unsigned short* xb = (unsigned short*)alloc((size_t)N * D * 2);       // bf16 of x
    int*   csrc   = (int*)alloc((size_t)E * 4);
    float* dis    = (float*)alloc((size_t)N * 4);
    int*   offs   = (int*)alloc((size_t)(N + 1) * 4);
    int*   ghist  = (int*)alloc((size_t)NBK * 4);
    int*   bstart = (int*)alloc((size_t)(NBK + 1) * 4);
    int*   gcur   = (int*)alloc((size_t)NBK * 4);
    float* sc     = (float*)alloc((size_t)LD * 4);
    float* sh     = (float*)alloc((size_t)LD * 4);
    float* gsum   = (float*)alloc((size_t)G * H2 * 4);
    int*   gstart = (int*)alloc((size_t)(G + 1) * 4);
    unsigned short* w1p  = (unsigned short*)alloc((size_t)LD * H1 * 2);   // enc1 bf16 packed
    unsigned short* w2p  = (unsigned short*)alloc((size_t)H1 * H2 * 2);   // enc2 bf16 packed
    unsigned short* wchi = (unsigned short*)alloc((size_t)L * D * D * 2); // conv hi packed
    unsigned short* wclo = (unsigned short*)alloc((size_t)L * D * D * 2); // conv lo packed
    unsigned* part = (unsigned*)bufB;            // dead before first conv (packed (row<<8)|(col&255))
    unsigned char* xw = (unsigned char*)bufB;    // fp8 e4m3 message table [N+1][64] (row N = zeros)

    hipMemsetAsync(ghist, 0, (size_t)NBK * 4, stream);
    hipMemsetAsync(gsum, 0, (size_t)G * H2 * 4, stream);

    int nchunks = (E + PCHUNK - 1) / PCHUNK;
    k_hist<<<nchunks, 256, NBK * 4, stream>>>(ei + E, ghist, E, NBK);
    k_bscan<<<1, 512, 0, stream>>>(ghist, bstart, gcur, offs, NBK, N, E);
    int partLds = (3 * NBK + 512) * 4 + PCHUNK * 4 + PCHUNK * 2;
    k_part<<<nchunks, 512, partLds, stream>>>(ei, ei + E, gcur, part, E, NBK);
    k_bucket<<<NBK, 256, 0, stream>>>(part, bstart, offs, dis, csrc, N);
    // zero row N of the xw table (divergence-tail gather target); part is dead now
    hipMemsetAsync(xw + (size_t)N * 64, 0, 64, stream);
    k_gb<<<1, 128, 0, stream>>>(batch, gstart, N, G);
    k_bnprep<<<(LD + 255) / 256, 256, 0, stream>>>(convb, gamma, beta, mean, var, sc, sh, LD);
    k_wpackb<<<(LD * H1 + 255) / 256, 256, 0, stream>>>(eW1, w1p, LD, H1, 8);
    k_wpackb<<<(H1 * H2 + 255) / 256, 256, 0, stream>>>(eW2, w2p, H1, H2, 7);
    for (int l = 0; l < L; ++l)
        k_wpack<<<(D * D + 255) / 256, 256, 0, stream>>>(convW + (size_t)l * D * D,
                                                         wchi + (size_t)l * D * D,
                                                         wclo + (size_t)l * D * D, D, D, 6);
    k_cast<<<(N * D / 8 + 255) / 256, 256, 0, stream>>>(x, xb, N * D / 8);

    size_t plane = (size_t)N * 64;
    for (int l = 0; l < L; ++l) {
        const unsigned short* Ain = (l == 0) ? xb : (localb + (size_t)(l - 1) * plane);
        k_convm<<<(N + 127) / 128, 256, 0, stream>>>(Ain,
                                                     wchi + (size_t)l * D * D,
                                                     wclo + (size_t)l * D * D,
                                                     dis, xw, N);
        // skip source: layer-0 fp32 plane (only l==2 uses it); fp32 out written only at l==0.
        const float* skip = (l % 2 == 0 && l != 0 && l != L - 1) ? local : nullptr;
        float* outf = (l == 0) ? local : nullptr;
        k_agg<<<(N + 31) / 32, 256, 0, stream>>>(xw, offs, csrc, dis, sc + (size_t)l * D,
                                                 sh + (size_t)l * D, skip,
                                                 outf,
                                                 localb + (size_t)l * plane, N);
    }

    // fused encoder (enc1 + enc2) + graph-sum pooling, BM=64
    k_enc<<<(N + 63) / 64, 512, 0, stream>>>(localb, plane, N, w1p, eb1, w2p, eb2,
                                             batch, gsum);

    k_dec<<<G, 256, 0, stream>>>(gsum, gstart, dW1, db1, dW2, db2, (float*)d_out, H2, HD);
}

// Round 15
// 450.280 us; speedup vs baseline: 1.0224x; 1.0224x over previous
//
#include <hip/hip_runtime.h>
#include <cstdint>
#include <cstddef>

#define D 64
#define SMAX 24
#define PCHUNK 8192
#define BCAP 12288

typedef __attribute__((ext_vector_type(8))) short short8;
typedef __attribute__((ext_vector_type(4))) float floatx4;
typedef __attribute__((ext_vector_type(2))) float floatx2;
typedef __attribute__((ext_vector_type(8))) _Float16 half8v;

__device__ inline unsigned short f2bf(float f) {   // RNE fp32 -> bf16
    unsigned u = __float_as_uint(f);
    unsigned r = 0x7FFFu + ((u >> 16) & 1u);
    return (unsigned short)((u + r) >> 16);
}
__device__ inline float bf2f(unsigned short h) {
    return __uint_as_float(((unsigned)h) << 16);
}
__device__ inline unsigned char f2fp8(float f) {   // fp32 -> fp8 e4m3 (OCP on gfx950)
    int pk = __builtin_amdgcn_cvt_pk_fp8_f32(f, f, 0, false);
    return (unsigned char)(pk & 0xFF);
}

// ---------------- bucket-partition CSR build ----------------

__global__ void k_hist(const int* __restrict__ col, int* __restrict__ ghist,
                       int E, int NBK) {
    extern __shared__ int lh[];
    int t = threadIdx.x;
    for (int i = t; i < NBK; i += 256) lh[i] = 0;
    __syncthreads();
    int base = blockIdx.x * 8192;
    int end = base + 8192; if (end > E) end = E;
    for (int e = base + t; e < end; e += 256) atomicAdd(&lh[col[e] >> 8], 1);
    __syncthreads();
    for (int i = t; i < NBK; i += 256) if (lh[i]) atomicAdd(&ghist[i], lh[i]);
}

__global__ void k_bscan(const int* __restrict__ ghist, int* __restrict__ bstart,
                        int* __restrict__ gcur, int* __restrict__ offs,
                        int NBK, int N, int E) {
    __shared__ int s[512];
    int t = threadIdx.x;
    int v = (t < NBK) ? ghist[t] : 0;
    s[t] = v; __syncthreads();
    for (int off = 1; off < 512; off <<= 1) {
        int x = (t >= off) ? s[t - off] : 0;
        __syncthreads();
        s[t] += x;
        __syncthreads();
    }
    int excl = s[t] - v;
    if (t < NBK) { bstart[t] = excl; gcur[t] = excl; }
    if (t == 0) { bstart[NBK] = E; offs[N] = E; }
}

// Block-level counting sort: each 8192-edge chunk is sorted by bucket (col>>8)
// in LDS, then written out coalesced. Record packed to 4B: (row<<8)|(col&255).
__global__ __launch_bounds__(512) void k_part(const int* __restrict__ row,
                                              const int* __restrict__ col,
                                              int* __restrict__ gcur,
                                              unsigned* __restrict__ part,
                                              int E, int NBK) {
    extern __shared__ int sm[];
    int* cnt    = sm;                  // NBK: per-bucket count
    int* cursor = sm + NBK;            // NBK: scatter cursor (starts at lstart)
    int* delta  = sm + 2 * NBK;        // NBK: gbase - lstart
    int* s      = sm + 3 * NBK;        // 512: scan buffer
    unsigned* sbuf = (unsigned*)(sm + 3 * NBK + 512);       // PCHUNK sorted records
    unsigned short* bkt = (unsigned short*)(sbuf + PCHUNK); // PCHUNK bucket ids

    int t = threadIdx.x;
    int base = blockIdx.x * PCHUNK;
    int end = base + PCHUNK; if (end > E) end = E;
    int nloc = end - base;

    for (int i = t; i < NBK; i += 512) cnt[i] = 0;
    __syncthreads();

    // pass 1: read col (once), histogram, keep col in registers
    int carr[16];
#pragma unroll
    for (int i = 0; i < 16; ++i) {
        int e = base + t + i * 512;
        int c = -1;
        if (e < end) {
            c = col[e];
            atomicAdd(&cnt[c >> 8], 1);
        }
        carr[i] = c;
    }
    __syncthreads();

    // exclusive scan over NBK buckets (512-wide Hillis-Steele, 1 elem/thread)
    int v0 = (t < NBK) ? cnt[t] : 0;
    s[t] = v0;
    __syncthreads();
    for (int off = 1; off < 512; off <<= 1) {
        int x = (t >= off) ? s[t - off] : 0;
        __syncthreads();
        s[t] += x;
        __syncthreads();
    }
    // s[i] inclusive; lstart = s[i] - cnt[i]. Reserve global ranges.
    for (int i = t; i < NBK; i += 512) {
        int c = cnt[i];
        int lst = s[i] - c;
        cursor[i] = lst;
        int gb = c ? atomicAdd(&gcur[i], c) : 0;
        delta[i] = gb - lst;
    }
    __syncthreads();

    // pass 2: read row (once), scatter packed record into LDS sorted order
#pragma unroll
    for (int i = 0; i < 16; ++i) {
        int c = carr[i];
        if (c >= 0) {
            int e = base + t + i * 512;
            int b = c >> 8;
            int p = atomicAdd(&cursor[b], 1);
            sbuf[p] = ((unsigned)row[e] << 8) | (unsigned)(c & 255);
            bkt[p] = (unsigned short)b;
        }
    }
    __syncthreads();

    // writeout: consecutive lanes -> consecutive global addresses per run
    for (int p = t; p < nloc; p += 512) {
        int b = bkt[p];
        part[p + delta[b]] = sbuf[p];
    }
}

// Per-bucket CSR finalize. csrc stores BYTE offsets into the fp8 xw table (row<<6).
__global__ __launch_bounds__(256) void k_bucket(const unsigned* __restrict__ part,
                                                const int* __restrict__ bstart,
                                                int* __restrict__ offs,
                                                float* __restrict__ dis,
                                                int* __restrict__ csrc, int N) {
    __shared__ int ncnt[256];
    __shared__ int s[256];
    __shared__ int lcur[256];
    __shared__ unsigned sb[BCAP];
    int b = blockIdx.x;
    int t = threadIdx.x;
    int n0 = b << 8;
    int e0 = bstart[b], e1 = bstart[b + 1];
    int nloc = e1 - e0;
    bool fits = nloc <= BCAP;
    ncnt[t] = 0;
    __syncthreads();
    if (fits) {
        for (int e = t; e < nloc; e += 256) {
            unsigned pr = part[e0 + e];
            sb[e] = pr;
            atomicAdd(&ncnt[pr & 255u], 1);
        }
    } else {
        for (int e = e0 + t; e < e1; e += 256) {
            unsigned pr = part[e];
            atomicAdd(&ncnt[pr & 255u], 1);
        }
    }
    __syncthreads();
    int v = ncnt[t];
    s[t] = v; __syncthreads();
    for (int off = 1; off < 256; off <<= 1) {
        int x = (t >= off) ? s[t - off] : 0;
        __syncthreads();
        s[t] += x;
        __syncthreads();
    }
    int excl = s[t] - v;
    int node = n0 + t;
    if (node < N) {
        offs[node] = e0 + excl;
        dis[node] = rsqrtf((float)(v + 1));
    }
    lcur[t] = excl;
    __syncthreads();
    if (fits) {
        for (int e = t; e < nloc; e += 256) {
            unsigned pr = sb[e];
            int p = atomicAdd(&lcur[pr & 255u], 1);
            csrc[e0 + p] = (int)(pr >> 8) << 6;
        }
    } else {
        for (int e = e0 + t; e < e1; e += 256) {
            unsigned pr = part[e];
            int p = atomicAdd(&lcur[pr & 255u], 1);
            csrc[e0 + p] = (int)(pr >> 8) << 6;
        }
    }
}

// graph boundaries
__global__ void k_gb(const int* __restrict__ batch, int* __restrict__ gstart,
                     int N, int G) {
    int g = threadIdx.x;
    if (g > G) return;
    int lo = 0, hi = N;
    while (lo < hi) {
        int mid = (lo + hi) >> 1;
        if (batch[mid] < g) lo = mid + 1; else hi = mid;
    }
    gstart[g] = lo;
}

// fold BN (eval) + conv bias into per-channel scale/shift
__global__ void k_bnprep(const float* __restrict__ cb, const float* __restrict__ g,
                         const float* __restrict__ be, const float* __restrict__ mu,
                         const float* __restrict__ var, float* __restrict__ sc,
                         float* __restrict__ sh, int LD) {
    int i = blockIdx.x * 256 + threadIdx.x;
    if (i < LD) {
        float s = g[i] * rsqrtf(var[i] + 1e-5f);
        sc[i] = s;
        sh[i] = (cb[i] - mu[i]) * s + be[i];
    }
}

// split fp32 weights into bf16 hi/lo, packed in MFMA fragment order:
// (k,n) -> chunk c=k/32, ntile=n/64, j=(n&63)>>4, lane=((k&31)>>3)*16+(n&15), kidx=k&7
__global__ void k_wpack(const float* __restrict__ B, unsigned short* __restrict__ hiP,
                        unsigned short* __restrict__ loP, int K, int Nc, int nshift) {
    int idx = blockIdx.x * 256 + threadIdx.x;
    if (idx >= K * Nc) return;
    int k = idx >> nshift;
    int n = idx & (Nc - 1);
    float a = B[idx];
    unsigned b = __float_as_uint(a);
    unsigned hb = b & 0xFFFF0000u;
    float ah = __uint_as_float(hb);
    float al = a - ah;
    int c = k >> 5;
    int ntile = n >> 6;
    int j = (n & 63) >> 4;
    int lane = ((k & 31) >> 3) * 16 + (n & 15);
    int kidx = k & 7;
    size_t o = ((((size_t)c * (Nc >> 6) + ntile) * 4 + j) * 64 + lane) * 8 + kidx;
    hiP[o] = (unsigned short)(hb >> 16);
    loP[o] = (unsigned short)(__float_as_uint(al) >> 16);
}

// bf16-only (RNE) fragment-packed weights (encoder)
__global__ void k_wpackb(const float* __restrict__ B, unsigned short* __restrict__ P,
                         int K, int Nc, int nshift) {
    int idx = blockIdx.x * 256 + threadIdx.x;
    if (idx >= K * Nc) return;
    int k = idx >> nshift;
    int n = idx & (Nc - 1);
    int c = k >> 5;
    int ntile = n >> 6;
    int j = (n & 63) >> 4;
    int lane = ((k & 31) >> 3) * 16 + (n & 15);
    int kidx = k & 7;
    size_t o = ((((size_t)c * (Nc >> 6) + ntile) * 4 + j) * 64 + lane) * 8 + kidx;
    P[o] = f2bf(B[idx]);
}

// cast fp32 -> bf16 (RNE), 8 elems/thread
__global__ void k_cast(const float* __restrict__ x, unsigned short* __restrict__ xb,
                       int n8) {
    int i = blockIdx.x * 256 + threadIdx.x;
    if (i >= n8) return;
    const float4* p = (const float4*)(x + (size_t)i * 8);
    float4 v0 = p[0], v1 = p[1];
    short8 o;
    o[0] = (short)f2bf(v0.x); o[1] = (short)f2bf(v0.y);
    o[2] = (short)f2bf(v0.z); o[3] = (short)f2bf(v0.w);
    o[4] = (short)f2bf(v1.x); o[5] = (short)f2bf(v1.y);
    o[6] = (short)f2bf(v1.z); o[7] = (short)f2bf(v1.w);
    *(short8*)(xb + (size_t)i * 8) = o;
}

// ---------------- conv GEMM via MFMA: xw' = fp8((A_bf16 @ (Whi+Wlo)) * dis[row]) ----------------
// K=64 (2 chunks, fully unrolled). Wave tile m=32 x n=64. Block = 4 waves -> BM=128.

__global__ __launch_bounds__(256) void k_convm(const unsigned short* __restrict__ A,
                                               const unsigned short* __restrict__ Whi,
                                               const unsigned short* __restrict__ Wlo,
                                               const float* __restrict__ dis,
                                               unsigned char* __restrict__ out, int N) {
    int t = threadIdx.x;
    int lane = t & 63;
    int l16 = lane & 15;
    int quad = lane >> 4;
    int w = t >> 6;
    int bm = blockIdx.x * 128 + w * 32;

    floatx4 acc[2][4];
#pragma unroll
    for (int i = 0; i < 2; ++i)
#pragma unroll
        for (int j = 0; j < 4; ++j) acc[i][j] = (floatx4)0.f;

    int r0 = bm + l16; if (r0 > N - 1) r0 = N - 1;
    int r1 = bm + 16 + l16; if (r1 > N - 1) r1 = N - 1;
    const unsigned short* a0 = A + (size_t)r0 * 64 + quad * 8;
    const unsigned short* a1 = A + (size_t)r1 * 64 + quad * 8;
    const unsigned short* bp = Whi + lane * 8;
    size_t loOff = (size_t)(Wlo - Whi);

    short8 a0c[2], a1c[2], bh[2][4], bl[2][4];
#pragma unroll
    for (int c = 0; c < 2; ++c) {
        a0c[c] = *(const short8*)(a0 + c * 32);
        a1c[c] = *(const short8*)(a1 + c * 32);
#pragma unroll
        for (int j = 0; j < 4; ++j) {
            bh[c][j] = *(const short8*)(bp + c * 2048 + j * 512);
            bl[c][j] = *(const short8*)(bp + loOff + c * 2048 + j * 512);
        }
    }
#pragma unroll
    for (int c = 0; c < 2; ++c) {
#pragma unroll
        for (int j = 0; j < 4; ++j) {
            acc[0][j] = __builtin_amdgcn_mfma_f32_16x16x32_bf16(a0c[c], bl[c][j], acc[0][j], 0, 0, 0);
            acc[0][j] = __builtin_amdgcn_mfma_f32_16x16x32_bf16(a0c[c], bh[c][j], acc[0][j], 0, 0, 0);
            acc[1][j] = __builtin_amdgcn_mfma_f32_16x16x32_bf16(a1c[c], bl[c][j], acc[1][j], 0, 0, 0);
            acc[1][j] = __builtin_amdgcn_mfma_f32_16x16x32_bf16(a1c[c], bh[c][j], acc[1][j], 0, 0, 0);
        }
    }
#pragma unroll
    for (int i = 0; i < 2; ++i) {
#pragma unroll
        for (int r = 0; r < 4; ++r) {
            int m = bm + i * 16 + quad * 4 + r;
            if (m < N) {
                float dv = dis[m];
                unsigned char* op = out + (size_t)m * 64 + l16;
#pragma unroll
                for (int j = 0; j < 4; ++j)
                    op[j * 16] = f2fp8(acc[i][j][r] * dv);
            }
        }
    }
}

// ---------------- aggregation: 8 nodes/wave, 8 chan-lanes per node, fp8 table ----------------
// 16-deep gather unroll (16 outstanding 64B-line requests per thread) to push the
// latency x concurrency product; VGPR ~56 stays under the 64-reg occupancy step.

__global__ __launch_bounds__(256) void k_agg(const unsigned char* __restrict__ xw,
                                             const int* __restrict__ offs,
                                             const int* __restrict__ src,
                                             const float* __restrict__ dis,
                                             const float* __restrict__ sc,
                                             const float* __restrict__ sh,
                                             const float* __restrict__ skip,
                                             float* __restrict__ out,
                                             unsigned short* __restrict__ outb,
                                             int N) {
    int t = threadIdx.x;
    int lane = t & 63;
    int w = t >> 6;
    int g = lane >> 3;          // node slot 0..7 within wave
    int cg = lane & 7;          // channel group: 8 fp8 channels (8 B)
    int c0 = cg * 8;
    int v = blockIdx.x * 32 + w * 8 + g;
    int vc = (v < N) ? v : N - 1;
    int e0 = offs[vc], e1 = offs[vc + 1];
    int deg = (v < N) ? (e1 - e0) : 0;
    const int* sp = src + e0;
    const unsigned char* xb = xw + (cg << 3);
    int zoff = N << 6;          // zero row (row N of xw is zeroed)

    // wave-max degree across the 8 node groups
    int dm = deg;
    dm = max(dm, __shfl_xor(dm, 8));
    dm = max(dm, __shfl_xor(dm, 16));
    dm = max(dm, __shfl_xor(dm, 32));

    floatx2 a01 = (floatx2)0.f, a23 = (floatx2)0.f;
    floatx2 a45 = (floatx2)0.f, a67 = (floatx2)0.f;

    int gbase = g << 3;
    for (int k = 0; k < dm; k += 16) {
        int i0 = k + cg;
        int i1 = k + 8 + cg;
        int sv0 = sp[(i0 < deg) ? i0 : 0];      // coalesced: 16 consecutive srcs/group
        int sv1 = sp[(i1 < deg) ? i1 : 0];
        uint2 m[16];
#pragma unroll
        for (int j = 0; j < 8; ++j) {
            int o = __shfl(sv0, gbase + j);
            o = (k + j < deg) ? o : zoff;
            m[j] = *(const uint2*)(xb + o);
        }
#pragma unroll
        for (int j = 0; j < 8; ++j) {
            int o = __shfl(sv1, gbase + j);
            o = (k + 8 + j < deg) ? o : zoff;
            m[8 + j] = *(const uint2*)(xb + o);
        }
#pragma unroll
        for (int j = 0; j < 16; ++j) {
            a01 += __builtin_amdgcn_cvt_pk_f32_fp8(m[j].x, false);
            a23 += __builtin_amdgcn_cvt_pk_f32_fp8(m[j].x, true);
            a45 += __builtin_amdgcn_cvt_pk_f32_fp8(m[j].y, false);
            a67 += __builtin_amdgcn_cvt_pk_f32_fp8(m[j].y, true);
        }
    }

    if (v < N) {
        uint2 ar = *(const uint2*)(xb + ((size_t)vc << 6));   // self loop
        a01 += __builtin_amdgcn_cvt_pk_f32_fp8(ar.x, false);
        a23 += __builtin_amdgcn_cvt_pk_f32_fp8(ar.x, true);
        a45 += __builtin_amdgcn_cvt_pk_f32_fp8(ar.y, false);
        a67 += __builtin_amdgcn_cvt_pk_f32_fp8(ar.y, true);
        float u[8];
        u[0] = a01[0]; u[1] = a01[1]; u[2] = a23[0]; u[3] = a23[1];
        u[4] = a45[0]; u[5] = a45[1]; u[6] = a67[0]; u[7] = a67[1];
        float dv = dis[vc];
        float4 S0 = *(const float4*)&sc[c0];
        float4 S1 = *(const float4*)&sc[c0 + 4];
        float4 H0 = *(const float4*)&sh[c0];
        float4 H1 = *(const float4*)&sh[c0 + 4];
        float sv[8], hv[8];
        sv[0] = S0.x; sv[1] = S0.y; sv[2] = S0.z; sv[3] = S0.w;
        sv[4] = S1.x; sv[5] = S1.y; sv[6] = S1.z; sv[7] = S1.w;
        hv[0] = H0.x; hv[1] = H0.y; hv[2] = H0.z; hv[3] = H0.w;
        hv[4] = H1.x; hv[5] = H1.y; hv[6] = H1.z; hv[7] = H1.w;
        float y[8];
#pragma unroll
        for (int q = 0; q < 8; ++q)
            y[q] = fmaxf(fmaf(u[q] * dv, sv[q], hv[q]), 0.f);
        size_t ob = (size_t)v * 64 + c0;
        if (skip) {
            float4 k0v = *(const float4*)(skip + ob);
            float4 k1v = *(const float4*)(skip + ob + 4);
            y[0] += k0v.x; y[1] += k0v.y; y[2] += k0v.z; y[3] += k0v.w;
            y[4] += k1v.x; y[5] += k1v.y; y[6] += k1v.z; y[7] += k1v.w;
        }
        if (out) {
            float4 o0, o1;
            o0.x = y[0]; o0.y = y[1]; o0.z = y[2]; o0.w = y[3];
            o1.x = y[4]; o1.y = y[5]; o1.z = y[6]; o1.w = y[7];
            *(float4*)(out + ob) = o0;
            *(float4*)(out + ob + 4) = o1;
        }
        short8 b8;
#pragma unroll
        for (int q = 0; q < 8; ++q) b8[q] = (short)f2bf(y[q]);
        *(short8*)(outb + ob) = b8;
    }
}

// ---------------- fused encoder + pool: h2 = relu(relu(A@W1+b1)@W2+b2), pooled into gsum ----
// BM=64 rows/block, 512 threads (8 waves = 2 row-groups x 4 col-waves).

__global__ __launch_bounds__(512) void k_enc(const unsigned short* __restrict__ A,
                                             size_t pplane, int M,
                                             const unsigned short* __restrict__ BP1,
                                             const float* __restrict__ bias1,
                                             const unsigned short* __restrict__ BP2,
                                             const float* __restrict__ bias2,
                                             const int* __restrict__ batch,
                                             float* __restrict__ gsum) {
    __shared__ unsigned short As[64 * 264];   // A tile [64][256+8]; later h1 tile
    __shared__ int bt[64];
    __shared__ int badf;
    const int KP = 264;
    int t = threadIdx.x;
    int lane = t & 63;
    int l16 = lane & 15;
    int quad = lane >> 4;
    int w = t >> 6;          // 0..7
    int nw = w & 3;          // col-wave
    int mg = w >> 2;         // row-group
    int bm = blockIdx.x * 64;

    if (t == 0) badf = 0;
    if (t < 64) bt[t] = batch[min(bm + t, M - 1)];

    // stage A tile: 64 rows x 256 cols from 4 planes (coalesced 16B segments)
    for (int q = t; q < 2048; q += 512) {
        int r = q >> 5;
        int s = q & 31;
        int gr = bm + r; if (gr > M - 1) gr = M - 1;
        int p = s >> 3;
        int i = s & 7;
        *(short8*)(As + r * KP + s * 8) =
            *(const short8*)(A + (size_t)p * pplane + (size_t)gr * 64 + i * 8);
    }
    __syncthreads();

    if (t < 64) {
        int b = bt[t];
        if (b != bt[0] && b != bt[63]) badf = 1;   // >2 segments: pathological
    }

    // ---- enc1: wave (mg,nw) computes h1[32mg..][64nw..64nw+64), K=256 (NC=8) ----
    int n0 = nw * 64;
    floatx4 acc[2][4];
#pragma unroll
    for (int i = 0; i < 2; ++i)
#pragma unroll
        for (int j = 0; j < 4; ++j) acc[i][j] = (floatx4)0.f;

    const unsigned short* a0 = As + (mg * 32 + l16) * KP + quad * 8;
    const unsigned short* a1 = a0 + 16 * KP;
    const unsigned short* bp1 = BP1 + ((size_t)(n0 >> 6) * 4) * 512 + lane * 8;

    short8 B[2][4];
#pragma unroll
    for (int s = 0; s < 2; ++s)
#pragma unroll
        for (int j = 0; j < 4; ++j)
            B[s][j] = *(const short8*)(bp1 + (size_t)s * 8192 + j * 512);

    for (int c = 0; c < 8; ++c) {
        int nc = (c + 2 < 8) ? c + 2 : 7;
        short8 tB[4];
#pragma unroll
        for (int j = 0; j < 4; ++j)
            tB[j] = *(const short8*)(bp1 + (size_t)nc * 8192 + j * 512);
        short8 A0 = *(const short8*)(a0 + c * 32);
        short8 A1 = *(const short8*)(a1 + c * 32);
#pragma unroll
        for (int j = 0; j < 4; ++j) {
            acc[0][j] = __builtin_amdgcn_mfma_f32_16x16x32_bf16(A0, B[0][j], acc[0][j], 0, 0, 0);
            acc[1][j] = __builtin_amdgcn_mfma_f32_16x16x32_bf16(A1, B[0][j], acc[1][j], 0, 0, 0);
        }
#pragma unroll
        for (int j = 0; j < 4; ++j) B[0][j] = B[1][j];
#pragma unroll
        for (int j = 0; j < 4; ++j) B[1][j] = tB[j];
    }

    __syncthreads();   // all waves done reading the A tile

    // write h1 = relu(acc + b1) as bf16 into As (row-major [64][256], KP pad kept)
#pragma unroll
    for (int i = 0; i < 2; ++i)
#pragma unroll
        for (int r = 0; r < 4; ++r) {
            int ml = mg * 32 + i * 16 + quad * 4 + r;
#pragma unroll
            for (int j = 0; j < 4; ++j) {
                float y = fmaxf(acc[i][j][r] + bias1[n0 + j * 16 + l16], 0.f);
                As[ml * KP + n0 + j * 16 + l16] = f2bf(y);
            }
        }
    __syncthreads();

    // ---- enc2: wave (mg,nw) computes h2[32mg..][32nw..32nw+32), K=256 (NC=8) ----
    int n0b = nw * 32;
    floatx4 acc2[2][2];
#pragma unroll
    for (int i = 0; i < 2; ++i)
#pragma unroll
        for (int j = 0; j < 2; ++j) acc2[i][j] = (floatx4)0.f;

    const unsigned short* bp2 = BP2 +
        ((size_t)((n0b >> 6) * 4 + ((n0b & 63) >> 4))) * 512 + lane * 8;

    for (int c = 0; c < 8; ++c) {
        short8 A0 = *(const short8*)(a0 + c * 32);
        short8 A1 = *(const short8*)(a1 + c * 32);
        short8 B0 = *(const short8*)(bp2 + (size_t)c * 4096);
        short8 B1 = *(const short8*)(bp2 + (size_t)c * 4096 + 512);
        acc2[0][0] = __builtin_amdgcn_mfma_f32_16x16x32_bf16(A0, B0, acc2[0][0], 0, 0, 0);
        acc2[0][1] = __builtin_amdgcn_mfma_f32_16x16x32_bf16(A0, B1, acc2[0][1], 0, 0, 0);
        acc2[1][0] = __builtin_amdgcn_mfma_f32_16x16x32_bf16(A1, B0, acc2[1][0], 0, 0, 0);
        acc2[1][1] = __builtin_amdgcn_mfma_f32_16x16x32_bf16(A1, B1, acc2[1][1], 0, 0, 0);
    }

    // ---- pooled epilogue: segment-reduce rows by graph, atomicAdd into gsum ----
    int g0 = bt[0], g1 = bt[63];
    if (!badf) {
#pragma unroll
        for (int j = 0; j < 2; ++j) {
            float s0 = 0.f, s1 = 0.f;
#pragma unroll
            for (int i = 0; i < 2; ++i)
#pragma unroll
                for (int r = 0; r < 4; ++r) {
                    int ml = mg * 32 + i * 16 + quad * 4 + r;
                    if (bm + ml < M) {
                        float y = fmaxf(acc2[i][j][r] + bias2[n0b + j * 16 + l16], 0.f);
                        bool f = (bt[ml] != g0);
                        s0 += f ? 0.f : y;
                        s1 += f ? y : 0.f;
                    }
                }
            s0 += __shfl_xor(s0, 16); s0 += __shfl_xor(s0, 32);
            s1 += __shfl_xor(s1, 16); s1 += __shfl_xor(s1, 32);
            if (quad == 0) {
                int cb = n0b + j * 16 + l16;
                atomicAdd(&gsum[(size_t)g0 * 128 + cb], s0);
                if (g1 != g0) atomicAdd(&gsum[(size_t)g1 * 128 + cb], s1);
            }
        }
    } else {
#pragma unroll
        for (int j = 0; j < 2; ++j)
#pragma unroll
            for (int i = 0; i < 2; ++i)
#pragma unroll
                for (int r = 0; r < 4; ++r) {
                    int ml = mg * 32 + i * 16 + quad * 4 + r;
                    if (bm + ml < M) {
                        float y = fmaxf(acc2[i][j][r] + bias2[n0b + j * 16 + l16], 0.f);
                        atomicAdd(&gsum[(size_t)bt[ml] * 128 + n0b + j * 16 + l16], y);
                    }
                }
    }
}

// ---------------- decoder: 4 waves x 32-k-chunk, fully unrolled (H=128, HD=64) ----------------

__global__ __launch_bounds__(256) void k_dec(const float* __restrict__ gsum, const int* __restrict__ gstart,
                      const float* __restrict__ W1, const float* __restrict__ b1,
                      const float* __restrict__ W2, const float* __restrict__ b2,
                      float* __restrict__ out, int H, int HD) {
    __shared__ float red[4][64];
    int g = blockIdx.x;
    int t = threadIdx.x;
    int c = t & 63;
    int kk = t >> 6;
    float cnt = (float)(gstart[g + 1] - gstart[g]);
    float inv = 1.0f / fmaxf(cnt, 1.0f);
    const float* gp = gsum + (size_t)g * 128 + kk * 32;
    const float* wp = W1 + (size_t)(kk * 32) * 64 + c;
    float a0 = 0.f, a1 = 0.f, a2 = 0.f, a3 = 0.f;
#pragma unroll
    for (int j = 0; j < 32; j += 4) {
        float g0 = gp[j + 0], g1 = gp[j + 1], g2 = gp[j + 2], g3 = gp[j + 3];
        float w0 = wp[(j + 0) * 64], w1 = wp[(j + 1) * 64];
        float w2 = wp[(j + 2) * 64], w3 = wp[(j + 3) * 64];
        a0 = fmaf(g0, w0, a0);
        a1 = fmaf(g1, w1, a1);
        a2 = fmaf(g2, w2, a2);
        a3 = fmaf(g3, w3, a3);
    }
    red[kk][c] = (a0 + a1) + (a2 + a3);
    __syncthreads();
    if (kk == 0) {
        float hid = ((red[0][c] + red[1][c]) + (red[2][c] + red[3][c])) * inv + b1[c];
        hid = fmaxf(hid, 0.f);
        float p = hid * W2[c];
        for (int off = 32; off > 0; off >>= 1) p += __shfl_down(p, off);
        if (c == 0) out[g] = p + b2[0];
    }
}

// ---------------- host ----------------

extern "C" void kernel_launch(void* const* d_in, const int* in_sizes, int n_in,
                              void* d_out, int out_size, void* d_ws, size_t ws_size,
                              hipStream_t stream) {
    const float* x     = (const float*)d_in[0];
    const int*   ei    = (const int*)d_in[1];
    const int*   batch = (const int*)d_in[2];
    const float* convW = (const float*)d_in[3];
    const float* convb = (const float*)d_in[4];
    const float* gamma = (const float*)d_in[5];
    const float* beta  = (const float*)d_in[6];
    const float* mean  = (const float*)d_in[7];
    const float* var   = (const float*)d_in[8];
    const float* eW1   = (const float*)d_in[9];
    const float* eb1   = (const float*)d_in[10];
    const float* eW2   = (const float*)d_in[11];
    const float* eb2   = (const float*)d_in[12];
    const float* dW1   = (const float*)d_in[13];
    const float* db1   = (const float*)d_in[14];
    const float* dW2   = (const float*)d_in[15];
    const float* db2   = (const float*)d_in[16];

    int N  = in_sizes[0] / D;
    int E  = in_sizes[1] / 2;
    int L  = in_sizes[3] / (D * D);
    int G  = out_size;
    int LD = L * D;                 // 256
    int H1 = in_sizes[10];          // 256
    int H2 = in_sizes[12];          // 128
    int HD = in_sizes[14];          // 64
    int NBK = (N + 255) >> 8;       // 391

    char* ws = (char*)d_ws;
    size_t off = 0;
    auto alloc = [&](size_t b) -> void* {
        void* p = ws + off;
        off += (b + 255) & ~(size_t)255;
        return p;
    };
    float* local  = (float*)alloc((size_t)N * D * 4);         // fp32 layer0 plane (skip source)
    unsigned short* localb = (unsigned short*)alloc((size_t)N * LD * 2);  // bf16 planes [L][N][64]
    char*  bufB   = (char*)alloc((size_t)(N + 1) * LD * 2);   // part / xw fp8 (+zero row)
    unsigned short* xb = (unsigned short*)alloc((size_t)N * D * 2);       // bf16 of x
    int*   csrc   = (int*)alloc((size_t)E * 4);
    float* dis    = (float*)alloc((size_t)N * 4);
    int*   offs   = (int*)alloc((size_t)(N + 1) * 4);
    int*   ghist  = (int*)alloc((size_t)NBK * 4);
    int*   bstart = (int*)alloc((size_t)(NBK + 1) * 4);
    int*   gcur   = (int*)alloc((size_t)NBK * 4);
    float* sc     = (float*)alloc((size_t)LD * 4);
    float* sh     = (float*)alloc((size_t)LD * 4);
    float* gsum   = (float*)alloc((size_t)G * H2 * 4);
    int*   gstart = (int*)alloc((size_t)(G + 1) * 4);
    unsigned short* w1p  = (unsigned short*)alloc((size_t)LD * H1 * 2);   // enc1 bf16 packed
    unsigned short* w2p  = (unsigned short*)alloc((size_t)H1 * H2 * 2);   // enc2 bf16 packed
    unsigned short* wchi = (unsigned short*)alloc((size_t)L * D * D * 2); // conv hi packed
    unsigned short* wclo = (unsigned short*)alloc((size_t)L * D * D * 2); // conv lo packed
    unsigned* part = (unsigned*)bufB;            // dead before first conv (packed (row<<8)|(col&255))
    unsigned char* xw = (unsigned char*)bufB;    // fp8 e4m3 message table [N+1][64] (row N = zeros)

    hipMemsetAsync(ghist, 0, (size_t)NBK * 4, stream);
    hipMemsetAsync(gsum, 0, (size_t)G * H2 * 4, stream);

    int nchunks = (E + PCHUNK - 1) / PCHUNK;
    k_hist<<<nchunks, 256, NBK * 4, stream>>>(ei + E, ghist, E, NBK);
    k_bscan<<<1, 512, 0, stream>>>(ghist, bstart, gcur, offs, NBK, N, E);
    int partLds = (3 * NBK + 512) * 4 + PCHUNK * 4 + PCHUNK * 2;
    k_part<<<nchunks, 512, partLds, stream>>>(ei, ei + E, gcur, part, E, NBK);
    k_bucket<<<NBK, 256, 0, stream>>>(part, bstart, offs, dis, csrc, N);
    // zero row N of the xw table (divergence-tail gather target); part is dead now
    hipMemsetAsync(xw + (size_t)N * 64, 0, 64, stream);
    k_gb<<<1, 128, 0, stream>>>(batch, gstart, N, G);
    k_bnprep<<<(LD + 255) / 256, 256, 0, stream>>>(convb, gamma, beta, mean, var, sc, sh, LD);
    k_wpackb<<<(LD * H1 + 255) / 256, 256, 0, stream>>>(eW1, w1p, LD, H1, 8);
    k_wpackb<<<(H1 * H2 + 255) / 256, 256, 0, stream>>>(eW2, w2p, H1, H2, 7);
    for (int l = 0; l < L; ++l)
        k_wpack<<<(D * D + 255) / 256, 256, 0, stream>>>(convW + (size_t)l * D * D,
                                                         wchi + (size_t)l * D * D,
                                                         wclo + (size_t)l * D * D, D, D, 6);
    k_cast<<<(N * D / 8 + 255) / 256, 256, 0, stream>>>(x, xb, N * D / 8);

    size_t plane = (size_t)N * 64;
    for (int l = 0; l < L; ++l) {
        const unsigned short* Ain = (l == 0) ? xb : (localb + (size_t)(l - 1) * plane);
        k_convm<<<(N + 127) / 128, 256, 0, stream>>>(Ain,
                                                     wchi + (size_t)l * D * D,
                                                     wclo + (size_t)l * D * D,
                                                     dis, xw, N);
        // skip source: layer-0 fp32 plane (only l==2 uses it); fp32 out written only at l==0.
        const float* skip = (l % 2 == 0 && l != 0 && l != L - 1) ? local : nullptr;
        float* outf = (l == 0) ? local : nullptr;
        k_agg<<<(N + 31) / 32, 256, 0, stream>>>(xw, offs, csrc, dis, sc + (size_t)l * D,
                                                 sh + (size_t)l * D, skip,
                                                 outf,
                                                 localb + (size_t)l * plane, N);
    }

    // fused encoder (enc1 + enc2) + graph-sum pooling, BM=64
    k_enc<<<(N + 63) / 64, 512, 0, stream>>>(localb, plane, N, w1p, eb1, w2p, eb2,
                                             batch, gsum);

    k_dec<<<G, 256, 0, stream>>>(gsum, gstart, dW1, db1, dW2, db2, (float*)d_out, H2, HD);
}

// Round 16
// 449.463 us; speedup vs baseline: 1.0243x; 1.0018x over previous
//
#include <hip/hip_runtime.h>
#include <cstdint>
#include <cstddef>

#define D 64
#define SMAX 24
#define PCHUNK 4096
#define BCAP 12288

typedef __attribute__((ext_vector_type(8))) short short8;
typedef __attribute__((ext_vector_type(4))) float floatx4;
typedef __attribute__((ext_vector_type(2))) float floatx2;
typedef __attribute__((ext_vector_type(8))) _Float16 half8v;

__device__ inline unsigned short f2bf(float f) {   // RNE fp32 -> bf16
    unsigned u = __float_as_uint(f);
    unsigned r = 0x7FFFu + ((u >> 16) & 1u);
    return (unsigned short)((u + r) >> 16);
}
__device__ inline float bf2f(unsigned short h) {
    return __uint_as_float(((unsigned)h) << 16);
}
__device__ inline unsigned char f2fp8(float f) {   // fp32 -> fp8 e4m3 (OCP on gfx950)
    int pk = __builtin_amdgcn_cvt_pk_fp8_f32(f, f, 0, false);
    return (unsigned char)(pk & 0xFF);
}

// ---------------- bucket-partition CSR build ----------------

__global__ void k_hist(const int* __restrict__ col, int* __restrict__ ghist,
                       int E, int NBK) {
    extern __shared__ int lh[];
    int t = threadIdx.x;
    for (int i = t; i < NBK; i += 256) lh[i] = 0;
    __syncthreads();
    int base = blockIdx.x * 8192;
    int end = base + 8192; if (end > E) end = E;
    for (int e = base + t; e < end; e += 256) atomicAdd(&lh[col[e] >> 8], 1);
    __syncthreads();
    for (int i = t; i < NBK; i += 256) if (lh[i]) atomicAdd(&ghist[i], lh[i]);
}

__global__ void k_bscan(const int* __restrict__ ghist, int* __restrict__ bstart,
                        int* __restrict__ gcur, int* __restrict__ offs,
                        int NBK, int N, int E) {
    __shared__ int s[512];
    int t = threadIdx.x;
    int v = (t < NBK) ? ghist[t] : 0;
    s[t] = v; __syncthreads();
    for (int off = 1; off < 512; off <<= 1) {
        int x = (t >= off) ? s[t - off] : 0;
        __syncthreads();
        s[t] += x;
        __syncthreads();
    }
    int excl = s[t] - v;
    if (t < NBK) { bstart[t] = excl; gcur[t] = excl; }
    if (t == 0) { bstart[NBK] = E; offs[N] = E; }
}

// Block-level counting sort: each PCHUNK-edge chunk is sorted by bucket (col>>8)
// in LDS, then written out coalesced. Record packed to 4B: (row<<8)|(col&255).
// PCHUNK=4096 @ 512 threads: ~31KB LDS -> ~5 blocks/CU resident (was 1.5 at 8192).
__global__ __launch_bounds__(512) void k_part(const int* __restrict__ row,
                                              const int* __restrict__ col,
                                              int* __restrict__ gcur,
                                              unsigned* __restrict__ part,
                                              int E, int NBK) {
    extern __shared__ int sm[];
    int* cnt    = sm;                  // NBK: per-bucket count
    int* cursor = sm + NBK;            // NBK: scatter cursor (starts at lstart)
    int* delta  = sm + 2 * NBK;        // NBK: gbase - lstart
    int* s      = sm + 3 * NBK;        // 512: scan buffer
    unsigned* sbuf = (unsigned*)(sm + 3 * NBK + 512);       // PCHUNK sorted records
    unsigned short* bkt = (unsigned short*)(sbuf + PCHUNK); // PCHUNK bucket ids

    int t = threadIdx.x;
    int base = blockIdx.x * PCHUNK;
    int end = base + PCHUNK; if (end > E) end = E;
    int nloc = end - base;

    for (int i = t; i < NBK; i += 512) cnt[i] = 0;
    __syncthreads();

    // pass 1: read col (once), histogram, keep col in registers
    int carr[8];
#pragma unroll
    for (int i = 0; i < 8; ++i) {
        int e = base + t + i * 512;
        int c = -1;
        if (e < end) {
            c = col[e];
            atomicAdd(&cnt[c >> 8], 1);
        }
        carr[i] = c;
    }
    __syncthreads();

    // exclusive scan over NBK buckets (512-wide Hillis-Steele, 1 elem/thread)
    int v0 = (t < NBK) ? cnt[t] : 0;
    s[t] = v0;
    __syncthreads();
    for (int off = 1; off < 512; off <<= 1) {
        int x = (t >= off) ? s[t - off] : 0;
        __syncthreads();
        s[t] += x;
        __syncthreads();
    }
    // s[i] inclusive; lstart = s[i] - cnt[i]. Reserve global ranges.
    for (int i = t; i < NBK; i += 512) {
        int c = cnt[i];
        int lst = s[i] - c;
        cursor[i] = lst;
        int gb = c ? atomicAdd(&gcur[i], c) : 0;
        delta[i] = gb - lst;
    }
    __syncthreads();

    // pass 2: read row (once), scatter packed record into LDS sorted order
#pragma unroll
    for (int i = 0; i < 8; ++i) {
        int c = carr[i];
        if (c >= 0) {
            int e = base + t + i * 512;
            int b = c >> 8;
            int p = atomicAdd(&cursor[b], 1);
            sbuf[p] = ((unsigned)row[e] << 8) | (unsigned)(c & 255);
            bkt[p] = (unsigned short)b;
        }
    }
    __syncthreads();

    // writeout: consecutive lanes -> consecutive global addresses per run
    for (int p = t; p < nloc; p += 512) {
        int b = bkt[p];
        part[p + delta[b]] = sbuf[p];
    }
}

// Per-bucket CSR finalize. csrc stores BYTE offsets into the fp8 xw table (row<<6).
__global__ __launch_bounds__(256) void k_bucket(const unsigned* __restrict__ part,
                                                const int* __restrict__ bstart,
                                                int* __restrict__ offs,
                                                float* __restrict__ dis,
                                                int* __restrict__ csrc, int N) {
    __shared__ int ncnt[256];
    __shared__ int s[256];
    __shared__ int lcur[256];
    __shared__ unsigned sb[BCAP];
    int b = blockIdx.x;
    int t = threadIdx.x;
    int n0 = b << 8;
    int e0 = bstart[b], e1 = bstart[b + 1];
    int nloc = e1 - e0;
    bool fits = nloc <= BCAP;
    ncnt[t] = 0;
    __syncthreads();
    if (fits) {
        for (int e = t; e < nloc; e += 256) {
            unsigned pr = part[e0 + e];
            sb[e] = pr;
            atomicAdd(&ncnt[pr & 255u], 1);
        }
    } else {
        for (int e = e0 + t; e < e1; e += 256) {
            unsigned pr = part[e];
            atomicAdd(&ncnt[pr & 255u], 1);
        }
    }
    __syncthreads();
    int v = ncnt[t];
    s[t] = v; __syncthreads();
    for (int off = 1; off < 256; off <<= 1) {
        int x = (t >= off) ? s[t - off] : 0;
        __syncthreads();
        s[t] += x;
        __syncthreads();
    }
    int excl = s[t] - v;
    int node = n0 + t;
    if (node < N) {
        offs[node] = e0 + excl;
        dis[node] = rsqrtf((float)(v + 1));
    }
    lcur[t] = excl;
    __syncthreads();
    if (fits) {
        for (int e = t; e < nloc; e += 256) {
            unsigned pr = sb[e];
            int p = atomicAdd(&lcur[pr & 255u], 1);
            csrc[e0 + p] = (int)(pr >> 8) << 6;
        }
    } else {
        for (int e = e0 + t; e < e1; e += 256) {
            unsigned pr = part[e];
            int p = atomicAdd(&lcur[pr & 255u], 1);
            csrc[e0 + p] = (int)(pr >> 8) << 6;
        }
    }
}

// graph boundaries
__global__ void k_gb(const int* __restrict__ batch, int* __restrict__ gstart,
                     int N, int G) {
    int g = threadIdx.x;
    if (g > G) return;
    int lo = 0, hi = N;
    while (lo < hi) {
        int mid = (lo + hi) >> 1;
        if (batch[mid] < g) lo = mid + 1; else hi = mid;
    }
    gstart[g] = lo;
}

// fold BN (eval) + conv bias into per-channel scale/shift
__global__ void k_bnprep(const float* __restrict__ cb, const float* __restrict__ g,
                         const float* __restrict__ be, const float* __restrict__ mu,
                         const float* __restrict__ var, float* __restrict__ sc,
                         float* __restrict__ sh, int LD) {
    int i = blockIdx.x * 256 + threadIdx.x;
    if (i < LD) {
        float s = g[i] * rsqrtf(var[i] + 1e-5f);
        sc[i] = s;
        sh[i] = (cb[i] - mu[i]) * s + be[i];
    }
}

// split fp32 weights into bf16 hi/lo, packed in MFMA fragment order:
// (k,n) -> chunk c=k/32, ntile=n/64, j=(n&63)>>4, lane=((k&31)>>3)*16+(n&15), kidx=k&7
__global__ void k_wpack(const float* __restrict__ B, unsigned short* __restrict__ hiP,
                        unsigned short* __restrict__ loP, int K, int Nc, int nshift) {
    int idx = blockIdx.x * 256 + threadIdx.x;
    if (idx >= K * Nc) return;
    int k = idx >> nshift;
    int n = idx & (Nc - 1);
    float a = B[idx];
    unsigned b = __float_as_uint(a);
    unsigned hb = b & 0xFFFF0000u;
    float ah = __uint_as_float(hb);
    float al = a - ah;
    int c = k >> 5;
    int ntile = n >> 6;
    int j = (n & 63) >> 4;
    int lane = ((k & 31) >> 3) * 16 + (n & 15);
    int kidx = k & 7;
    size_t o = ((((size_t)c * (Nc >> 6) + ntile) * 4 + j) * 64 + lane) * 8 + kidx;
    hiP[o] = (unsigned short)(hb >> 16);
    loP[o] = (unsigned short)(__float_as_uint(al) >> 16);
}

// bf16-only (RNE) fragment-packed weights (encoder)
__global__ void k_wpackb(const float* __restrict__ B, unsigned short* __restrict__ P,
                         int K, int Nc, int nshift) {
    int idx = blockIdx.x * 256 + threadIdx.x;
    if (idx >= K * Nc) return;
    int k = idx >> nshift;
    int n = idx & (Nc - 1);
    int c = k >> 5;
    int ntile = n >> 6;
    int j = (n & 63) >> 4;
    int lane = ((k & 31) >> 3) * 16 + (n & 15);
    int kidx = k & 7;
    size_t o = ((((size_t)c * (Nc >> 6) + ntile) * 4 + j) * 64 + lane) * 8 + kidx;
    P[o] = f2bf(B[idx]);
}

// cast fp32 -> bf16 (RNE), 8 elems/thread
__global__ void k_cast(const float* __restrict__ x, unsigned short* __restrict__ xb,
                       int n8) {
    int i = blockIdx.x * 256 + threadIdx.x;
    if (i >= n8) return;
    const float4* p = (const float4*)(x + (size_t)i * 8);
    float4 v0 = p[0], v1 = p[1];
    short8 o;
    o[0] = (short)f2bf(v0.x); o[1] = (short)f2bf(v0.y);
    o[2] = (short)f2bf(v0.z); o[3] = (short)f2bf(v0.w);
    o[4] = (short)f2bf(v1.x); o[5] = (short)f2bf(v1.y);
    o[6] = (short)f2bf(v1.z); o[7] = (short)f2bf(v1.w);
    *(short8*)(xb + (size_t)i * 8) = o;
}

// ---------------- conv GEMM via MFMA: xw' = fp8((A_bf16 @ (Whi+Wlo)) * dis[row]) ----------------
// K=64 (2 chunks, fully unrolled). Wave tile m=32 x n=64. Block = 4 waves -> BM=128.

__global__ __launch_bounds__(256) void k_convm(const unsigned short* __restrict__ A,
                                               const unsigned short* __restrict__ Whi,
                                               const unsigned short* __restrict__ Wlo,
                                               const float* __restrict__ dis,
                                               unsigned char* __restrict__ out, int N) {
    int t = threadIdx.x;
    int lane = t & 63;
    int l16 = lane & 15;
    int quad = lane >> 4;
    int w = t >> 6;
    int bm = blockIdx.x * 128 + w * 32;

    floatx4 acc[2][4];
#pragma unroll
    for (int i = 0; i < 2; ++i)
#pragma unroll
        for (int j = 0; j < 4; ++j) acc[i][j] = (floatx4)0.f;

    int r0 = bm + l16; if (r0 > N - 1) r0 = N - 1;
    int r1 = bm + 16 + l16; if (r1 > N - 1) r1 = N - 1;
    const unsigned short* a0 = A + (size_t)r0 * 64 + quad * 8;
    const unsigned short* a1 = A + (size_t)r1 * 64 + quad * 8;
    const unsigned short* bp = Whi + lane * 8;
    size_t loOff = (size_t)(Wlo - Whi);

    short8 a0c[2], a1c[2], bh[2][4], bl[2][4];
#pragma unroll
    for (int c = 0; c < 2; ++c) {
        a0c[c] = *(const short8*)(a0 + c * 32);
        a1c[c] = *(const short8*)(a1 + c * 32);
#pragma unroll
        for (int j = 0; j < 4; ++j) {
            bh[c][j] = *(const short8*)(bp + c * 2048 + j * 512);
            bl[c][j] = *(const short8*)(bp + loOff + c * 2048 + j * 512);
        }
    }
#pragma unroll
    for (int c = 0; c < 2; ++c) {
#pragma unroll
        for (int j = 0; j < 4; ++j) {
            acc[0][j] = __builtin_amdgcn_mfma_f32_16x16x32_bf16(a0c[c], bl[c][j], acc[0][j], 0, 0, 0);
            acc[0][j] = __builtin_amdgcn_mfma_f32_16x16x32_bf16(a0c[c], bh[c][j], acc[0][j], 0, 0, 0);
            acc[1][j] = __builtin_amdgcn_mfma_f32_16x16x32_bf16(a1c[c], bl[c][j], acc[1][j], 0, 0, 0);
            acc[1][j] = __builtin_amdgcn_mfma_f32_16x16x32_bf16(a1c[c], bh[c][j], acc[1][j], 0, 0, 0);
        }
    }
#pragma unroll
    for (int i = 0; i < 2; ++i) {
#pragma unroll
        for (int r = 0; r < 4; ++r) {
            int m = bm + i * 16 + quad * 4 + r;
            if (m < N) {
                float dv = dis[m];
                unsigned char* op = out + (size_t)m * 64 + l16;
#pragma unroll
                for (int j = 0; j < 4; ++j)
                    op[j * 16] = f2fp8(acc[i][j][r] * dv);
            }
        }
    }
}

// ---------------- aggregation: 8 nodes/wave, 8 chan-lanes per node, fp8 table ----------------
// 16-deep gather unroll (16 outstanding 64B-line requests per thread).

__global__ __launch_bounds__(256) void k_agg(const unsigned char* __restrict__ xw,
                                             const int* __restrict__ offs,
                                             const int* __restrict__ src,
                                             const float* __restrict__ dis,
                                             const float* __restrict__ sc,
                                             const float* __restrict__ sh,
                                             const float* __restrict__ skip,
                                             float* __restrict__ out,
                                             unsigned short* __restrict__ outb,
                                             int N) {
    int t = threadIdx.x;
    int lane = t & 63;
    int w = t >> 6;
    int g = lane >> 3;          // node slot 0..7 within wave
    int cg = lane & 7;          // channel group: 8 fp8 channels (8 B)
    int c0 = cg * 8;
    int v = blockIdx.x * 32 + w * 8 + g;
    int vc = (v < N) ? v : N - 1;
    int e0 = offs[vc], e1 = offs[vc + 1];
    int deg = (v < N) ? (e1 - e0) : 0;
    const int* sp = src + e0;
    const unsigned char* xb = xw + (cg << 3);
    int zoff = N << 6;          // zero row (row N of xw is zeroed)

    // wave-max degree across the 8 node groups
    int dm = deg;
    dm = max(dm, __shfl_xor(dm, 8));
    dm = max(dm, __shfl_xor(dm, 16));
    dm = max(dm, __shfl_xor(dm, 32));

    floatx2 a01 = (floatx2)0.f, a23 = (floatx2)0.f;
    floatx2 a45 = (floatx2)0.f, a67 = (floatx2)0.f;

    int gbase = g << 3;
    for (int k = 0; k < dm; k += 16) {
        int i0 = k + cg;
        int i1 = k + 8 + cg;
        int sv0 = sp[(i0 < deg) ? i0 : 0];      // coalesced: 16 consecutive srcs/group
        int sv1 = sp[(i1 < deg) ? i1 : 0];
        uint2 m[16];
#pragma unroll
        for (int j = 0; j < 8; ++j) {
            int o = __shfl(sv0, gbase + j);
            o = (k + j < deg) ? o : zoff;
            m[j] = *(const uint2*)(xb + o);
        }
#pragma unroll
        for (int j = 0; j < 8; ++j) {
            int o = __shfl(sv1, gbase + j);
            o = (k + 8 + j < deg) ? o : zoff;
            m[8 + j] = *(const uint2*)(xb + o);
        }
#pragma unroll
        for (int j = 0; j < 16; ++j) {
            a01 += __builtin_amdgcn_cvt_pk_f32_fp8(m[j].x, false);
            a23 += __builtin_amdgcn_cvt_pk_f32_fp8(m[j].x, true);
            a45 += __builtin_amdgcn_cvt_pk_f32_fp8(m[j].y, false);
            a67 += __builtin_amdgcn_cvt_pk_f32_fp8(m[j].y, true);
        }
    }

    if (v < N) {
        uint2 ar = *(const uint2*)(xb + ((size_t)vc << 6));   // self loop
        a01 += __builtin_amdgcn_cvt_pk_f32_fp8(ar.x, false);
        a23 += __builtin_amdgcn_cvt_pk_f32_fp8(ar.x, true);
        a45 += __builtin_amdgcn_cvt_pk_f32_fp8(ar.y, false);
        a67 += __builtin_amdgcn_cvt_pk_f32_fp8(ar.y, true);
        float u[8];
        u[0] = a01[0]; u[1] = a01[1]; u[2] = a23[0]; u[3] = a23[1];
        u[4] = a45[0]; u[5] = a45[1]; u[6] = a67[0]; u[7] = a67[1];
        float dv = dis[vc];
        float4 S0 = *(const float4*)&sc[c0];
        float4 S1 = *(const float4*)&sc[c0 + 4];
        float4 H0 = *(const float4*)&sh[c0];
        float4 H1 = *(const float4*)&sh[c0 + 4];
        float sv[8], hv[8];
        sv[0] = S0.x; sv[1] = S0.y; sv[2] = S0.z; sv[3] = S0.w;
        sv[4] = S1.x; sv[5] = S1.y; sv[6] = S1.z; sv[7] = S1.w;
        hv[0] = H0.x; hv[1] = H0.y; hv[2] = H0.z; hv[3] = H0.w;
        hv[4] = H1.x; hv[5] = H1.y; hv[6] = H1.z; hv[7] = H1.w;
        float y[8];
#pragma unroll
        for (int q = 0; q < 8; ++q)
            y[q] = fmaxf(fmaf(u[q] * dv, sv[q], hv[q]), 0.f);
        size_t ob = (size_t)v * 64 + c0;
        if (skip) {
            float4 k0v = *(const float4*)(skip + ob);
            float4 k1v = *(const float4*)(skip + ob + 4);
            y[0] += k0v.x; y[1] += k0v.y; y[2] += k0v.z; y[3] += k0v.w;
            y[4] += k1v.x; y[5] += k1v.y; y[6] += k1v.z; y[7] += k1v.w;
        }
        if (out) {
            float4 o0, o1;
            o0.x = y[0]; o0.y = y[1]; o0.z = y[2]; o0.w = y[3];
            o1.x = y[4]; o1.y = y[5]; o1.z = y[6]; o1.w = y[7];
            *(float4*)(out + ob) = o0;
            *(float4*)(out + ob + 4) = o1;
        }
        short8 b8;
#pragma unroll
        for (int q = 0; q < 8; ++q) b8[q] = (short)f2bf(y[q]);
        *(short8*)(outb + ob) = b8;
    }
}

// ---------------- fused encoder + pool: h2 = relu(relu(A@W1+b1)@W2+b2), pooled into gsum ----
// BM=64 rows/block, 512 threads (8 waves = 2 row-groups x 4 col-waves).
// enc2 now has the same 2-slot B prefetch pipeline as enc1.

__global__ __launch_bounds__(512) void k_enc(const unsigned short* __restrict__ A,
                                             size_t pplane, int M,
                                             const unsigned short* __restrict__ BP1,
                                             const float* __restrict__ bias1,
                                             const unsigned short* __restrict__ BP2,
                                             const float* __restrict__ bias2,
                                             const int* __restrict__ batch,
                                             float* __restrict__ gsum) {
    __shared__ unsigned short As[64 * 264];   // A tile [64][256+8]; later h1 tile
    __shared__ int bt[64];
    __shared__ int badf;
    const int KP = 264;
    int t = threadIdx.x;
    int lane = t & 63;
    int l16 = lane & 15;
    int quad = lane >> 4;
    int w = t >> 6;          // 0..7
    int nw = w & 3;          // col-wave
    int mg = w >> 2;         // row-group
    int bm = blockIdx.x * 64;

    if (t == 0) badf = 0;
    if (t < 64) bt[t] = batch[min(bm + t, M - 1)];

    // stage A tile: 64 rows x 256 cols from 4 planes (coalesced 16B segments)
    for (int q = t; q < 2048; q += 512) {
        int r = q >> 5;
        int s = q & 31;
        int gr = bm + r; if (gr > M - 1) gr = M - 1;
        int p = s >> 3;
        int i = s & 7;
        *(short8*)(As + r * KP + s * 8) =
            *(const short8*)(A + (size_t)p * pplane + (size_t)gr * 64 + i * 8);
    }
    __syncthreads();

    if (t < 64) {
        int b = bt[t];
        if (b != bt[0] && b != bt[63]) badf = 1;   // >2 segments: pathological
    }

    // ---- enc1: wave (mg,nw) computes h1[32mg..][64nw..64nw+64), K=256 (NC=8) ----
    int n0 = nw * 64;
    floatx4 acc[2][4];
#pragma unroll
    for (int i = 0; i < 2; ++i)
#pragma unroll
        for (int j = 0; j < 4; ++j) acc[i][j] = (floatx4)0.f;

    const unsigned short* a0 = As + (mg * 32 + l16) * KP + quad * 8;
    const unsigned short* a1 = a0 + 16 * KP;
    const unsigned short* bp1 = BP1 + ((size_t)(n0 >> 6) * 4) * 512 + lane * 8;

    short8 B[2][4];
#pragma unroll
    for (int s = 0; s < 2; ++s)
#pragma unroll
        for (int j = 0; j < 4; ++j)
            B[s][j] = *(const short8*)(bp1 + (size_t)s * 8192 + j * 512);

    for (int c = 0; c < 8; ++c) {
        int nc = (c + 2 < 8) ? c + 2 : 7;
        short8 tB[4];
#pragma unroll
        for (int j = 0; j < 4; ++j)
            tB[j] = *(const short8*)(bp1 + (size_t)nc * 8192 + j * 512);
        short8 A0 = *(const short8*)(a0 + c * 32);
        short8 A1 = *(const short8*)(a1 + c * 32);
#pragma unroll
        for (int j = 0; j < 4; ++j) {
            acc[0][j] = __builtin_amdgcn_mfma_f32_16x16x32_bf16(A0, B[0][j], acc[0][j], 0, 0, 0);
            acc[1][j] = __builtin_amdgcn_mfma_f32_16x16x32_bf16(A1, B[0][j], acc[1][j], 0, 0, 0);
        }
#pragma unroll
        for (int j = 0; j < 4; ++j) B[0][j] = B[1][j];
#pragma unroll
        for (int j = 0; j < 4; ++j) B[1][j] = tB[j];
    }

    __syncthreads();   // all waves done reading the A tile

    // write h1 = relu(acc + b1) as bf16 into As (row-major [64][256], KP pad kept)
#pragma unroll
    for (int i = 0; i < 2; ++i)
#pragma unroll
        for (int r = 0; r < 4; ++r) {
            int ml = mg * 32 + i * 16 + quad * 4 + r;
#pragma unroll
            for (int j = 0; j < 4; ++j) {
                float y = fmaxf(acc[i][j][r] + bias1[n0 + j * 16 + l16], 0.f);
                As[ml * KP + n0 + j * 16 + l16] = f2bf(y);
            }
        }
    __syncthreads();

    // ---- enc2: wave (mg,nw) computes h2[32mg..][32nw..32nw+32), K=256 (NC=8) ----
    int n0b = nw * 32;
    floatx4 acc2[2][2];
#pragma unroll
    for (int i = 0; i < 2; ++i)
#pragma unroll
        for (int j = 0; j < 2; ++j) acc2[i][j] = (floatx4)0.f;

    const unsigned short* bp2 = BP2 +
        ((size_t)((n0b >> 6) * 4 + ((n0b & 63) >> 4))) * 512 + lane * 8;

    short8 C[2][2];
#pragma unroll
    for (int s = 0; s < 2; ++s) {
        C[s][0] = *(const short8*)(bp2 + (size_t)s * 4096);
        C[s][1] = *(const short8*)(bp2 + (size_t)s * 4096 + 512);
    }

    for (int c = 0; c < 8; ++c) {
        int nc = (c + 2 < 8) ? c + 2 : 7;
        short8 tC0 = *(const short8*)(bp2 + (size_t)nc * 4096);
        short8 tC1 = *(const short8*)(bp2 + (size_t)nc * 4096 + 512);
        short8 A0 = *(const short8*)(a0 + c * 32);
        short8 A1 = *(const short8*)(a1 + c * 32);
        acc2[0][0] = __builtin_amdgcn_mfma_f32_16x16x32_bf16(A0, C[0][0], acc2[0][0], 0, 0, 0);
        acc2[0][1] = __builtin_amdgcn_mfma_f32_16x16x32_bf16(A0, C[0][1], acc2[0][1], 0, 0, 0);
        acc2[1][0] = __builtin_amdgcn_mfma_f32_16x16x32_bf16(A1, C[0][0], acc2[1][0], 0, 0, 0);
        acc2[1][1] = __builtin_amdgcn_mfma_f32_16x16x32_bf16(A1, C[0][1], acc2[1][1], 0, 0, 0);
        C[0][0] = C[1][0]; C[0][1] = C[1][1];
        C[1][0] = tC0;     C[1][1] = tC1;
    }

    // ---- pooled epilogue: segment-reduce rows by graph, atomicAdd into gsum ----
    int g0 = bt[0], g1 = bt[63];
    if (!badf) {
#pragma unroll
        for (int j = 0; j < 2; ++j) {
            float s0 = 0.f, s1 = 0.f;
#pragma unroll
            for (int i = 0; i < 2; ++i)
#pragma unroll
                for (int r = 0; r < 4; ++r) {
                    int ml = mg * 32 + i * 16 + quad * 4 + r;
                    if (bm + ml < M) {
                        float y = fmaxf(acc2[i][j][r] + bias2[n0b + j * 16 + l16], 0.f);
                        bool f = (bt[ml] != g0);
                        s0 += f ? 0.f : y;
                        s1 += f ? y : 0.f;
                    }
                }
            s0 += __shfl_xor(s0, 16); s0 += __shfl_xor(s0, 32);
            s1 += __shfl_xor(s1, 16); s1 += __shfl_xor(s1, 32);
            if (quad == 0) {
                int cb = n0b + j * 16 + l16;
                atomicAdd(&gsum[(size_t)g0 * 128 + cb], s0);
                if (g1 != g0) atomicAdd(&gsum[(size_t)g1 * 128 + cb], s1);
            }
        }
    } else {
#pragma unroll
        for (int j = 0; j < 2; ++j)
#pragma unroll
            for (int i = 0; i < 2; ++i)
#pragma unroll
                for (int r = 0; r < 4; ++r) {
                    int ml = mg * 32 + i * 16 + quad * 4 + r;
                    if (bm + ml < M) {
                        float y = fmaxf(acc2[i][j][r] + bias2[n0b + j * 16 + l16], 0.f);
                        atomicAdd(&gsum[(size_t)bt[ml] * 128 + n0b + j * 16 + l16], y);
                    }
                }
    }
}

// ---------------- decoder: 4 waves x 32-k-chunk, fully unrolled (H=128, HD=64) ----------------

__global__ __launch_bounds__(256) void k_dec(const float* __restrict__ gsum, const int* __restrict__ gstart,
                      const float* __restrict__ W1, const float* __restrict__ b1,
                      const float* __restrict__ W2, const float* __restrict__ b2,
                      float* __restrict__ out, int H, int HD) {
    __shared__ float red[4][64];
    int g = blockIdx.x;
    int t = threadIdx.x;
    int c = t & 63;
    int kk = t >> 6;
    float cnt = (float)(gstart[g + 1] - gstart[g]);
    float inv = 1.0f / fmaxf(cnt, 1.0f);
    const float* gp = gsum + (size_t)g * 128 + kk * 32;
    const float* wp = W1 + (size_t)(kk * 32) * 64 + c;
    float a0 = 0.f, a1 = 0.f, a2 = 0.f, a3 = 0.f;
#pragma unroll
    for (int j = 0; j < 32; j += 4) {
        float g0 = gp[j + 0], g1 = gp[j + 1], g2 = gp[j + 2], g3 = gp[j + 3];
        float w0 = wp[(j + 0) * 64], w1 = wp[(j + 1) * 64];
        float w2 = wp[(j + 2) * 64], w3 = wp[(j + 3) * 64];
        a0 = fmaf(g0, w0, a0);
        a1 = fmaf(g1, w1, a1);
        a2 = fmaf(g2, w2, a2);
        a3 = fmaf(g3, w3, a3);
    }
    red[kk][c] = (a0 + a1) + (a2 + a3);
    __syncthreads();
    if (kk == 0) {
        float hid = ((red[0][c] + red[1][c]) + (red[2][c] + red[3][c])) * inv + b1[c];
        hid = fmaxf(hid, 0.f);
        float p = hid * W2[c];
        for (int off = 32; off > 0; off >>= 1) p += __shfl_down(p, off);
        if (c == 0) out[g] = p + b2[0];
    }
}

// ---------------- host ----------------

extern "C" void kernel_launch(void* const* d_in, const int* in_sizes, int n_in,
                              void* d_out, int out_size, void* d_ws, size_t ws_size,
                              hipStream_t stream) {
    const float* x     = (const float*)d_in[0];
    const int*   ei    = (const int*)d_in[1];
    const int*   batch = (const int*)d_in[2];
    const float* convW = (const float*)d_in[3];
    const float* convb = (const float*)d_in[4];
    const float* gamma = (const float*)d_in[5];
    const float* beta  = (const float*)d_in[6];
    const float* mean  = (const float*)d_in[7];
    const float* var   = (const float*)d_in[8];
    const float* eW1   = (const float*)d_in[9];
    const float* eb1   = (const float*)d_in[10];
    const float* eW2   = (const float*)d_in[11];
    const float* eb2   = (const float*)d_in[12];
    const float* dW1   = (const float*)d_in[13];
    const float* db1   = (const float*)d_in[14];
    const float* dW2   = (const float*)d_in[15];
    const float* db2   = (const float*)d_in[16];

    int N  = in_sizes[0] / D;
    int E  = in_sizes[1] / 2;
    int L  = in_sizes[3] / (D * D);
    int G  = out_size;
    int LD = L * D;                 // 256
    int H1 = in_sizes[10];          // 256
    int H2 = in_sizes[12];          // 128
    int HD = in_sizes[14];          // 64
    int NBK = (N + 255) >> 8;       // 391

    char* ws = (char*)d_ws;
    size_t off = 0;
    auto alloc = [&](size_t b) -> void* {
        void* p = ws + off;
        off += (b + 255) & ~(size_t)255;
        return p;
    };
    float* local  = (float*)alloc((size_t)N * D * 4);         // fp32 layer0 plane (skip source)
    unsigned short* localb = (unsigned short*)alloc((size_t)N * LD * 2);  // bf16 planes [L][N][64]
    char*  bufB   = (char*)alloc((size_t)(N + 1) * LD * 2);   // part / xw fp8 (+zero row)
    unsigned short* xb = (unsigned short*)alloc((size_t)N * D * 2);       // bf16 of x
    int*   csrc   = (int*)alloc((size_t)E * 4);
    float* dis    = (float*)alloc((size_t)N * 4);
    int*   offs   = (int*)alloc((size_t)(N + 1) * 4);
    int*   ghist  = (int*)alloc((size_t)NBK * 4);
    int*   bstart = (int*)alloc((size_t)(NBK + 1) * 4);
    int*   gcur   = (int*)alloc((size_t)NBK * 4);
    float* sc     = (float*)alloc((size_t)LD * 4);
    float* sh     = (float*)alloc((size_t)LD * 4);
    float* gsum   = (float*)alloc((size_t)G * H2 * 4);
    int*   gstart = (int*)alloc((size_t)(G + 1) * 4);
    unsigned short* w1p  = (unsigned short*)alloc((size_t)LD * H1 * 2);   // enc1 bf16 packed
    unsigned short* w2p  = (unsigned short*)alloc((size_t)H1 * H2 * 2);   // enc2 bf16 packed
    unsigned short* wchi = (unsigned short*)alloc((size_t)L * D * D * 2); // conv hi packed
    unsigned short* wclo = (unsigned short*)alloc((size_t)L * D * D * 2); // conv lo packed
    unsigned* part = (unsigned*)bufB;            // dead before first conv (packed (row<<8)|(col&255))
    unsigned char* xw = (unsigned char*)bufB;    // fp8 e4m3 message table [N+1][64] (row N = zeros)

    hipMemsetAsync(ghist, 0, (size_t)NBK * 4, stream);
    hipMemsetAsync(gsum, 0, (size_t)G * H2 * 4, stream);

    int nhist = (E + 8191) / 8192;
    int nchunks = (E + PCHUNK - 1) / PCHUNK;
    k_hist<<<nhist, 256, NBK * 4, stream>>>(ei + E, ghist, E, NBK);
    k_bscan<<<1, 512, 0, stream>>>(ghist, bstart, gcur, offs, NBK, N, E);
    int partLds = (3 * NBK + 512) * 4 + PCHUNK * 4 + PCHUNK * 2;
    k_part<<<nchunks, 512, partLds, stream>>>(ei, ei + E, gcur, part, E, NBK);
    k_bucket<<<NBK, 256, 0, stream>>>(part, bstart, offs, dis, csrc, N);
    // zero row N of the xw table (divergence-tail gather target); part is dead now
    hipMemsetAsync(xw + (size_t)N * 64, 0, 64, stream);
    k_gb<<<1, 128, 0, stream>>>(batch, gstart, N, G);
    k_bnprep<<<(LD + 255) / 256, 256, 0, stream>>>(convb, gamma, beta, mean, var, sc, sh, LD);
    k_wpackb<<<(LD * H1 + 255) / 256, 256, 0, stream>>>(eW1, w1p, LD, H1, 8);
    k_wpackb<<<(H1 * H2 + 255) / 256, 256, 0, stream>>>(eW2, w2p, H1, H2, 7);
    for (int l = 0; l < L; ++l)
        k_wpack<<<(D * D + 255) / 256, 256, 0, stream>>>(convW + (size_t)l * D * D,
                                                         wchi + (size_t)l * D * D,
                                                         wclo + (size_t)l * D * D, D, D, 6);
    k_cast<<<(N * D / 8 + 255) / 256, 256, 0, stream>>>(x, xb, N * D / 8);

    size_t plane = (size_t)N * 64;
    for (int l = 0; l < L; ++l) {
        const unsigned short* Ain = (l == 0) ? xb : (localb + (size_t)(l - 1) * plane);
        k_convm<<<(N + 127) / 128, 256, 0, stream>>>(Ain,
                                                     wchi + (size_t)l * D * D,
                                                     wclo + (size_t)l * D * D,
                                                     dis, xw, N);
        // skip source: layer-0 fp32 plane (only l==2 uses it); fp32 out written only at l==0.
        const float* skip = (l % 2 == 0 && l != 0 && l != L - 1) ? local : nullptr;
        float* outf = (l == 0) ? local : nullptr;
        k_agg<<<(N + 31) / 32, 256, 0, stream>>>(xw, offs, csrc, dis, sc + (size_t)l * D,
                                                 sh + (size_t)l * D, skip,
                                                 outf,
                                                 localb + (size_t)l * plane, N);
    }

    // fused encoder (enc1 + enc2) + graph-sum pooling, BM=64
    k_enc<<<(N + 63) / 64, 512, 0, stream>>>(localb, plane, N, w1p, eb1, w2p, eb2,
                                             batch, gsum);

    k_dec<<<G, 256, 0, stream>>>(gsum, gstart, dW1, db1, dW2, db2, (float*)d_out, H2, HD);
}